// Round 13
// baseline (312.477 us; speedup 1.0000x reference)
//
#include <hip/hip_runtime.h>
#include <hip/hip_cooperative_groups.h>

namespace cg = cooperative_groups;

#define D_F 128
#define N_NODES 10000
#define N_EDGES 320000

// ---- workspace layout: FULL path ----
#define WS_AGG       0u
#define WS_RC        5120000u                  // E uints  (row | col<<16)
#define WS_RADM      6400000u                  // E float2 (radial, mask)
#define WS_COUNTS    8960000u                  // 10240 ints
#define WS_CURSOR    9000960u                  // 10240 ints
#define WS_FULL_NEED 9041920u

// ---- workspace layout: FALLBACK (R4) path ----
#define F_WS_COUNTS 5120000u
#define F_WS_CURSOR 5160960u
#define F_WS_PERM   5201920u
#define F_WS_NEED   (5201920u + 1280000u)

typedef short s16x8 __attribute__((ext_vector_type(8)));
typedef float f32x4 __attribute__((ext_vector_type(4)));

union FragU { s16x8 v; unsigned u[4]; };

__device__ __forceinline__ unsigned cvt_pk_bf16(float lo, float hi) {
  unsigned r;
  asm("v_cvt_pk_bf16_f32 %0, %1, %2" : "=v"(r) : "v"(lo), "v"(hi));
  return r;
}
__device__ __forceinline__ float bf2f(unsigned short b) {
  union { unsigned u; float f; } v; v.u = ((unsigned)b) << 16; return v.f;
}
__device__ __forceinline__ float silu_f(float x) {
  float t = __builtin_amdgcn_exp2f(x * -1.44269504089f);
  return x * __builtin_amdgcn_rcpf(1.0f + t);
}
__device__ __forceinline__ void bar_lds() {
  asm volatile("s_waitcnt lgkmcnt(0)" ::: "memory");
  __builtin_amdgcn_sched_barrier(0);
  __builtin_amdgcn_s_barrier();
  __builtin_amdgcn_sched_barrier(0);
}
__device__ __forceinline__ void bar_all() {
  asm volatile("s_waitcnt vmcnt(0) lgkmcnt(0)" ::: "memory");
  __builtin_amdgcn_sched_barrier(0);
  __builtin_amdgcn_s_barrier();
  __builtin_amdgcn_sched_barrier(0);
}
__device__ __forceinline__ void wait_vm0() {
  asm volatile("s_waitcnt vmcnt(0)" ::: "memory");
  __builtin_amdgcn_sched_barrier(0);
}
__device__ __forceinline__ void gload_lds16(const unsigned short* g, char* l) {
  __builtin_amdgcn_global_load_lds(
      (const __attribute__((address_space(1))) unsigned int*)g,
      (__attribute__((address_space(3))) unsigned int*)l, 16, 0, 0);
}

// ================= fused preprocessing (cooperative): prep+hist+scan+scatter ======
__global__ __launch_bounds__(256)
void fused_pre_kernel(const float* __restrict__ h, unsigned short* __restrict__ hbf,
                      float* __restrict__ agg, int* __restrict__ counts,
                      int* __restrict__ cursor, const int* __restrict__ ei,
                      const float* __restrict__ coord,
                      const float* __restrict__ edge_mask,
                      unsigned* __restrict__ rc, float2* __restrict__ radm) {
  cg::grid_group grid = cg::this_grid();
  const int tid = threadIdx.x;
  const int gid = blockIdx.x * 256 + tid;
  const int gsz = gridDim.x * 256;

  // phase 1: h -> bf16, zero agg, zero counts
  for (int i = gid; i < N_NODES * D_F / 4; i += gsz) {
    int j = i * 4;
    f32x4 v = *(const f32x4*)(h + j);
    *(unsigned*)(hbf + j)     = cvt_pk_bf16(v[0], v[1]);
    *(unsigned*)(hbf + j + 2) = cvt_pk_bf16(v[2], v[3]);
    *(f32x4*)(agg + j) = (f32x4){0.f, 0.f, 0.f, 0.f};
  }
  if (gid < 10240) counts[gid] = 0;
  grid.sync();

  // phase 2: histogram of rows
  for (int e = gid; e < N_EDGES; e += gsz)
    atomicAdd(&counts[ei[e]], 1);
  grid.sync();

  // phase 3: exclusive scan (block 0 only; 40 bins/thread, counts read twice)
  if (blockIdx.x == 0) {
    __shared__ int sd[256];
    const int base = tid * 40;
    int s = 0;
#pragma unroll 8
    for (int j = 0; j < 40; ++j) s += counts[base + j];
    sd[tid] = s;
    __syncthreads();
    for (int off = 1; off < 256; off <<= 1) {
      int v = sd[tid];
      int a = (tid >= off) ? sd[tid - off] : 0;
      __syncthreads();
      sd[tid] = v + a;
      __syncthreads();
    }
    int run = sd[tid] - s;  // exclusive prefix
#pragma unroll 8
    for (int j = 0; j < 40; ++j) {
      int c = counts[base + j];
      cursor[base + j] = run;
      run += c;
    }
  }
  grid.sync();

  // phase 4: scatter sorted flat arrays
  for (int e = gid; e < N_EDGES; e += gsz) {
    int r = ei[e], c = ei[N_EDGES + e];
    int pos = atomicAdd(&cursor[r], 1);
    float dx = coord[r * 3 + 0] - coord[c * 3 + 0];
    float dy = coord[r * 3 + 1] - coord[c * 3 + 1];
    float dz = coord[r * 3 + 2] - coord[c * 3 + 2];
    rc[pos] = (unsigned)r | ((unsigned)c << 16);
    radm[pos] = make_float2(dx * dx + dy * dy + dz * dz, edge_mask[e]);
  }
}

// ================= separate-kernel fallbacks (if coop launch unavailable) =========
__global__ __launch_bounds__(256)
void prep_kernel(const float* __restrict__ h, unsigned short* __restrict__ hbf,
                 float* __restrict__ agg, int* __restrict__ counts) {
  int g = blockIdx.x * 256 + threadIdx.x;
  int i = g * 4;
  if (i < N_NODES * D_F) {
    f32x4 v = *(const f32x4*)(h + i);
    *(unsigned*)(hbf + i)     = cvt_pk_bf16(v[0], v[1]);
    *(unsigned*)(hbf + i + 2) = cvt_pk_bf16(v[2], v[3]);
    *(f32x4*)(agg + i) = (f32x4){0.f, 0.f, 0.f, 0.f};
  }
  if (g < 10240) counts[g] = 0;
}

__global__ __launch_bounds__(256)
void hist_kernel(const int* __restrict__ ei, int* __restrict__ counts) {
  for (int e = blockIdx.x * 256 + threadIdx.x; e < N_EDGES; e += gridDim.x * 256)
    atomicAdd(&counts[ei[e]], 1);
}

__global__ __launch_bounds__(1024)
void scan_kernel(const int* __restrict__ counts, int* __restrict__ cursor) {
  __shared__ int sd[1024];
  const int t = threadIdx.x;
  const int base = t * 10;
  int loc[10]; int s = 0;
#pragma unroll
  for (int j = 0; j < 10; ++j) { loc[j] = counts[base + j]; s += loc[j]; }
  sd[t] = s;
  __syncthreads();
  for (int off = 1; off < 1024; off <<= 1) {
    int v = sd[t];
    int a = (t >= off) ? sd[t - off] : 0;
    __syncthreads();
    sd[t] = v + a;
    __syncthreads();
  }
  int run = sd[t] - s;
#pragma unroll
  for (int j = 0; j < 10; ++j) { cursor[base + j] = run; run += loc[j]; }
}

__global__ __launch_bounds__(256)
void scatter2_kernel(const int* __restrict__ ei, const float* __restrict__ coord,
                     const float* __restrict__ edge_mask, int* __restrict__ cursor,
                     unsigned* __restrict__ rc, float2* __restrict__ radm) {
  for (int e = blockIdx.x * 256 + threadIdx.x; e < N_EDGES; e += gridDim.x * 256) {
    int r = ei[e], c = ei[N_EDGES + e];
    int pos = atomicAdd(&cursor[r], 1);
    float dx = coord[r * 3 + 0] - coord[c * 3 + 0];
    float dy = coord[r * 3 + 1] - coord[c * 3 + 1];
    float dz = coord[r * 3 + 2] - coord[c * 3 + 2];
    rc[pos] = (unsigned)r | ((unsigned)c << 16);
    radm[pos] = make_float2(dx * dx + dy * dy + dz * dz, edge_mask[e]);
  }
}

__global__ __launch_bounds__(256)
void scatter_kernel(const int* __restrict__ ei, int* __restrict__ cursor,
                    int* __restrict__ perm) {
  for (int e = blockIdx.x * 256 + threadIdx.x; e < N_EDGES; e += gridDim.x * 256) {
    int r = ei[e];
    int p = atomicAdd(&cursor[r], 1);
    perm[p] = e;
  }
}

// ================= edge kernel (R12, 2 barriers/tile, 80us proven) ====
#define TE2   32
#define GRID2 512
#define NT2   (N_EDGES / TE2)   // 10000
#define E2_M1   32768u
#define E2_M2   40960u
#define E2_META 49152u
#define E2_LDS  50688u

__global__ __launch_bounds__(256)
void egcl_edge2(const unsigned short* __restrict__ hbf,
                const float* __restrict__ We1, const float* __restrict__ be1,
                const float* __restrict__ We2, const float* __restrict__ be2,
                const unsigned* __restrict__ rc, const float2* __restrict__ radm,
                float* __restrict__ agg) {
  extern __shared__ __attribute__((aligned(16))) char smem[];
  const int tid  = threadIdx.x;
  const int lane = tid & 63;
  const int wv   = tid >> 6;          // 0..3 : col group of 32
  const int l15  = lane & 15;
  const int lg   = lane >> 4;
  const int c0   = wv * 32;
  const int col0 = c0 + l15;
  const int le   = lane & 31;
  const int lh   = lane >> 5;

  FragU bw1[8][2];
  FragU bw2[4][2];
#pragma unroll
  for (int kt = 0; kt < 8; ++kt)
#pragma unroll
    for (int nt = 0; nt < 2; ++nt) {
      const int col = col0 + nt * 16;
      const int kb = kt * 32 + lg * 8;
#pragma unroll
      for (int j = 0; j < 4; ++j)
        bw1[kt][nt].u[j] = cvt_pk_bf16(We1[(kb + 2 * j) * D_F + col],
                                       We1[(kb + 2 * j + 1) * D_F + col]);
    }
#pragma unroll
  for (int kt = 0; kt < 4; ++kt)
#pragma unroll
    for (int nt = 0; nt < 2; ++nt) {
      const int col = col0 + nt * 16;
      const int kb = kt * 32 + lg * 8;
#pragma unroll
      for (int j = 0; j < 4; ++j)
        bw2[kt][nt].u[j] = cvt_pk_bf16(We2[(kb + 2 * j) * D_F + col],
                                       We2[(kb + 2 * j + 1) * D_F + col]);
    }
  const float bv1[2] = {be1[col0], be1[col0 + 16]};
  const float wlv[2] = {We1[256 * D_F + col0], We1[256 * D_F + col0 + 16]};
  const float bv2[2] = {be2[col0], be2[col0 + 16]};
  const unsigned rswz = (unsigned)((l15 & 7) << 4);

  const int bid = (int)blockIdx.x;
  int t = bid;
  unsigned crc; float2 crm;

  {
    crc = rc[t * TE2 + le];
    crm = radm[t * TE2 + le];
    if (tid < 32) {
      *(int*)(smem + E2_META + 0 + tid * 4)     = (int)(crc & 0xFFFFu);
      *(float*)(smem + E2_META + 128 + tid * 4) = crm.x;
      *(float*)(smem + E2_META + 256 + tid * 4) = crm.y;
    }
#pragma unroll
    for (int k = 0; k < 4; ++k) {
      int pr = wv * 4 + k;
      int cc = 2 * pr + lh;
      unsigned node = (cc < 16) ? (crc & 0xFFFFu) : (crc >> 16);
      gload_lds16(hbf + (size_t)node * D_F + (cc & 15) * 8,
                  smem + pr * 1024 + lane * 16);
    }
    int tn = t + GRID2; int tnc = (tn < NT2) ? tn : t;
    crc = rc[tnc * TE2 + le];
    crm = radm[tnc * TE2 + le];
  }
  bar_all();
  int p = 0;
  int ms = 0;

  for (; t < NT2; t += GRID2) {
    char* cur = smem + p * 16384;
    char* nxt = smem + (p ^ 1) * 16384;
    const int msn = (ms == 2) ? 0 : (ms + 1);
    const int mo = ms * 512, mn = msn * 512;
    int*   rowsL = (int*)(smem + E2_META + mo);
    float* radsL = (float*)(smem + E2_META + mo + 128);
    float* msksL = (float*)(smem + E2_META + mo + 256);

    {
#pragma unroll
      for (int k = 0; k < 4; ++k) {
        int pr = wv * 4 + k;
        int cc = 2 * pr + lh;
        unsigned node = (cc < 16) ? (crc & 0xFFFFu) : (crc >> 16);
        gload_lds16(hbf + (size_t)node * D_F + (cc & 15) * 8,
                    nxt + pr * 1024 + lane * 16);
      }
      if (tid < 32) {
        *(int*)(smem + E2_META + mn + 0 + tid * 4)     = (int)(crc & 0xFFFFu);
        *(float*)(smem + E2_META + mn + 128 + tid * 4) = crm.x;
        *(float*)(smem + E2_META + mn + 256 + tid * 4) = crm.y;
      }
    }
    int t2 = t + 2 * GRID2; int t2c = (t2 < NT2) ? t2 : bid;
    unsigned nrc = rc[t2c * TE2 + le];
    float2 nrm = radm[t2c * TE2 + le];

    f32x4 acc[2][2];
#pragma unroll
    for (int mt = 0; mt < 2; ++mt)
#pragma unroll
      for (int nt = 0; nt < 2; ++nt) acc[mt][nt] = (f32x4){0.f, 0.f, 0.f, 0.f};
    __builtin_amdgcn_s_setprio(1);
#pragma unroll
    for (int ks = 0; ks < 8; ++ks) {
      s16x8 a[2];
      const int chunk = ks * 4 + lg;
#pragma unroll
      for (int mt = 0; mt < 2; ++mt)
        a[mt] = *(const s16x8*)(cur + chunk * 512 + (mt * 16 + l15) * 16);
#pragma unroll
      for (int mt = 0; mt < 2; ++mt)
#pragma unroll
        for (int nt = 0; nt < 2; ++nt)
          acc[mt][nt] = __builtin_amdgcn_mfma_f32_16x16x32_bf16(a[mt], bw1[ks][nt].v,
                                                                acc[mt][nt], 0, 0, 0);
    }
    __builtin_amdgcn_s_setprio(0);

#pragma unroll
    for (int mt = 0; mt < 2; ++mt)
#pragma unroll
      for (int nt = 0; nt < 2; ++nt)
#pragma unroll
        for (int q = 0; q < 4; ++q) {
          int e = mt * 16 + lg * 4 + q;
          float v = acc[mt][nt][q] + bv1[nt] + radsL[e] * wlv[nt];
          v = silu_f(v);
          *(unsigned short*)(smem + E2_M1 + (unsigned)(e * 256) +
                             ((unsigned)((c0 + nt * 16 + l15) * 2) ^
                              ((unsigned)((e & 7) << 4)))) =
              (unsigned short)cvt_pk_bf16(v, v);
        }
    bar_lds();  // B1

    f32x4 acc2[2][2];
#pragma unroll
    for (int mt = 0; mt < 2; ++mt)
#pragma unroll
      for (int nt = 0; nt < 2; ++nt) acc2[mt][nt] = (f32x4){0.f, 0.f, 0.f, 0.f};
    __builtin_amdgcn_s_setprio(1);
#pragma unroll
    for (int ks = 0; ks < 4; ++ks) {
      s16x8 a[2];
      unsigned kb = ((unsigned)((ks * 32 + lg * 8) * 2)) ^ rswz;
#pragma unroll
      for (int mt = 0; mt < 2; ++mt)
        a[mt] = *(const s16x8*)(smem + E2_M1 +
                                (unsigned)((mt * 16 + l15) * 256) + kb);
#pragma unroll
      for (int mt = 0; mt < 2; ++mt)
#pragma unroll
        for (int nt = 0; nt < 2; ++nt)
          acc2[mt][nt] = __builtin_amdgcn_mfma_f32_16x16x32_bf16(a[mt], bw2[ks][nt].v,
                                                                 acc2[mt][nt], 0, 0, 0);
    }
    __builtin_amdgcn_s_setprio(0);
#pragma unroll
    for (int mt = 0; mt < 2; ++mt)
#pragma unroll
      for (int nt = 0; nt < 2; ++nt)
#pragma unroll
        for (int q = 0; q < 4; ++q) {
          int e = mt * 16 + lg * 4 + q;
          float v = silu_f(acc2[mt][nt][q] + bv2[nt]) * msksL[e];
          int col = c0 + nt * 16 + l15;
          *(unsigned short*)(smem + E2_M2 + (unsigned)(e * 256) +
                             ((unsigned)(col * 2) ^ ((unsigned)((e & 7) << 4)))) =
              (unsigned short)cvt_pk_bf16(v, v);
        }
    wait_vm0();
    bar_lds();  // B2

    {
      const int q4 = tid >> 7, colw = tid & 127;
      const int eb = q4 * 16;
      float a = 0.f;
      int curR = rowsL[eb];
#pragma unroll
      for (int i = 0; i < 16; ++i) {
        int e = eb + i;
        float v = bf2f(*(const unsigned short*)(
            smem + E2_M2 + (unsigned)(e * 256) +
            ((unsigned)(colw * 2) ^ ((unsigned)((e & 7) << 4)))));
        int r = rowsL[e];
        if (r != curR) {
          atomicAdd(agg + (size_t)curR * D_F + colw, a);
          a = 0.f; curR = r;
        }
        a += v;
      }
      atomicAdd(agg + (size_t)curR * D_F + colw, a);
    }
    crc = nrc; crm = nrm; p ^= 1; ms = msn;
  }
}

// ================= fallback edge kernel (R4, proven) =================
#define F_OFF_A    0u
#define F_OFF_M2   0u
#define F_OFF_M1   32768u
#define F_OFF_META 49152u
#define F_EDGE_LDS (49152u + 1024u)
#define NTILES (N_EDGES / 64)

template <bool SORTED>
__global__ __launch_bounds__(256)
void egcl_edge_fb(const float* __restrict__ h, const float* __restrict__ coord,
                  const float* __restrict__ edge_mask,
                  const float* __restrict__ We1, const float* __restrict__ be1,
                  const float* __restrict__ We2, const float* __restrict__ be2,
                  const int* __restrict__ ei, const int* __restrict__ perm,
                  float* __restrict__ agg) {
  extern __shared__ __attribute__((aligned(16))) char smem[];
  const int tid  = threadIdx.x;
  const int lane = tid & 63;
  const int wv   = tid >> 6;
  const int l15  = lane & 15;
  const int lg   = lane >> 4;
  const int c0   = wv * 32;
  const int col0 = c0 + l15;

  int*   rows = (int*)(smem + F_OFF_META);
  float* rads = (float*)(smem + F_OFF_META + 256);
  float* msks = (float*)(smem + F_OFF_META + 512);

  FragU bw1[8][2];
  FragU bw2[4][2];
#pragma unroll
  for (int kt = 0; kt < 8; ++kt)
#pragma unroll
    for (int nt = 0; nt < 2; ++nt) {
      const int col = col0 + nt * 16;
      const int kb = kt * 32 + lg * 8;
#pragma unroll
      for (int j = 0; j < 4; ++j)
        bw1[kt][nt].u[j] = cvt_pk_bf16(We1[(kb + 2 * j) * D_F + col],
                                       We1[(kb + 2 * j + 1) * D_F + col]);
    }
#pragma unroll
  for (int kt = 0; kt < 4; ++kt)
#pragma unroll
    for (int nt = 0; nt < 2; ++nt) {
      const int col = col0 + nt * 16;
      const int kb = kt * 32 + lg * 8;
#pragma unroll
      for (int j = 0; j < 4; ++j)
        bw2[kt][nt].u[j] = cvt_pk_bf16(We2[(kb + 2 * j) * D_F + col],
                                       We2[(kb + 2 * j + 1) * D_F + col]);
    }
  const float bv1[2] = {be1[col0], be1[col0 + 16]};
  const float wlv[2] = {We1[256 * D_F + col0], We1[256 * D_F + col0 + 16]};
  const float bv2[2] = {be2[col0], be2[col0 + 16]};

  const int se = tid >> 2;
  const int sq = tid & 3;
  const unsigned sswz = (unsigned)((se & 7) << 4);
  const unsigned rswz = (unsigned)((l15 & 7) << 4);

  for (int tile = (int)blockIdx.x; tile < NTILES; tile += (int)gridDim.x) {
    const int ebase = tile * 64;
    const int eidx = SORTED ? perm[ebase + se] : (ebase + se);
    const int n0 = ei[eidx];
    const int n1 = ei[N_EDGES + eidx];
    if (sq == 0) {
      float dx = coord[n0 * 3 + 0] - coord[n1 * 3 + 0];
      float dy = coord[n0 * 3 + 1] - coord[n1 * 3 + 1];
      float dz = coord[n0 * 3 + 2] - coord[n1 * 3 + 2];
      rows[se] = n0;
      rads[se] = dx * dx + dy * dy + dz * dz;
      msks[se] = edge_mask[eidx];
    }
#pragma unroll
    for (int pp = 0; pp < 2; ++pp) {
      const f32x4* src = (const f32x4*)(h + (pp ? n1 : n0) * D_F + sq * 32);
#pragma unroll
      for (int j = 0; j < 4; ++j) {
        f32x4 x0 = src[2 * j], x1 = src[2 * j + 1];
        FragU w;
        w.u[0] = cvt_pk_bf16(x0[0], x0[1]);
        w.u[1] = cvt_pk_bf16(x0[2], x0[3]);
        w.u[2] = cvt_pk_bf16(x1[0], x1[1]);
        w.u[3] = cvt_pk_bf16(x1[2], x1[3]);
        unsigned kb = (unsigned)(pp * 256 + sq * 64 + j * 16);
        *(s16x8*)(smem + F_OFF_A + (unsigned)(se * 512) + (kb ^ sswz)) = w.v;
      }
    }
    bar_lds();

    f32x4 acc[4][2];
#pragma unroll
    for (int mt = 0; mt < 4; ++mt)
#pragma unroll
      for (int nt = 0; nt < 2; ++nt) acc[mt][nt] = (f32x4){0.f, 0.f, 0.f, 0.f};
#pragma unroll
    for (int ks = 0; ks < 8; ++ks) {
      s16x8 a[4];
      unsigned kb = ((unsigned)((ks * 32 + lg * 8) * 2)) ^ rswz;
#pragma unroll
      for (int mt = 0; mt < 4; ++mt)
        a[mt] = *(const s16x8*)(smem + F_OFF_A + (unsigned)((mt * 16 + l15) * 512) + kb);
#pragma unroll
      for (int mt = 0; mt < 4; ++mt)
#pragma unroll
        for (int nt = 0; nt < 2; ++nt)
          acc[mt][nt] = __builtin_amdgcn_mfma_f32_16x16x32_bf16(a[mt], bw1[ks][nt].v,
                                                                acc[mt][nt], 0, 0, 0);
    }
#pragma unroll
    for (int mt = 0; mt < 4; ++mt)
#pragma unroll
      for (int nt = 0; nt < 2; ++nt)
#pragma unroll
        for (int q = 0; q < 4; ++q) {
          int e = mt * 16 + lg * 4 + q;
          float v = acc[mt][nt][q] + bv1[nt] + rads[e] * wlv[nt];
          v = silu_f(v);
          *(unsigned short*)(smem + F_OFF_M1 + (unsigned)(e * 256) +
                             ((unsigned)((c0 + nt * 16 + l15) * 2) ^
                              ((unsigned)((e & 7) << 4)))) =
              (unsigned short)cvt_pk_bf16(v, v);
        }
    bar_lds();

#pragma unroll
    for (int mt = 0; mt < 4; ++mt)
#pragma unroll
      for (int nt = 0; nt < 2; ++nt) acc[mt][nt] = (f32x4){0.f, 0.f, 0.f, 0.f};
#pragma unroll
    for (int ks = 0; ks < 4; ++ks) {
      s16x8 a[4];
      unsigned kb = ((unsigned)((ks * 32 + lg * 8) * 2)) ^ rswz;
#pragma unroll
      for (int mt = 0; mt < 4; ++mt)
        a[mt] = *(const s16x8*)(smem + F_OFF_M1 + (unsigned)((mt * 16 + l15) * 256) + kb);
#pragma unroll
      for (int mt = 0; mt < 4; ++mt)
#pragma unroll
        for (int nt = 0; nt < 2; ++nt)
          acc[mt][nt] = __builtin_amdgcn_mfma_f32_16x16x32_bf16(a[mt], bw2[ks][nt].v,
                                                                acc[mt][nt], 0, 0, 0);
    }
    if (SORTED) {
#pragma unroll
      for (int mt = 0; mt < 4; ++mt)
#pragma unroll
        for (int nt = 0; nt < 2; ++nt)
#pragma unroll
          for (int q = 0; q < 4; ++q) {
            int e = mt * 16 + lg * 4 + q;
            float v = silu_f(acc[mt][nt][q] + bv2[nt]) * msks[e];
            int col = c0 + nt * 16 + l15;
            *(unsigned short*)(smem + F_OFF_M2 + (unsigned)(e * 256) +
                               ((unsigned)(col * 2) ^ ((unsigned)((e & 7) << 4)))) =
                (unsigned short)cvt_pk_bf16(v, v);
          }
      bar_lds();
      {
        const int colw = tid & 127, half = tid >> 7;
        float a = 0.f;
        int cur = rows[half * 32];
#pragma unroll 8
        for (int i = 0; i < 32; ++i) {
          int e = half * 32 + i;
          float v = bf2f(*(const unsigned short*)(
              smem + F_OFF_M2 + (unsigned)(e * 256) +
              ((unsigned)(colw * 2) ^ ((unsigned)((e & 7) << 4)))));
          int r = rows[e];
          if (r != cur) { atomicAdd(agg + (size_t)cur * D_F + colw, a); a = 0.f; cur = r; }
          a += v;
        }
        atomicAdd(agg + (size_t)cur * D_F + colw, a);
      }
    } else {
#pragma unroll
      for (int mt = 0; mt < 4; ++mt)
#pragma unroll
        for (int q = 0; q < 4; ++q) {
          int e = mt * 16 + lg * 4 + q;
          int r = rows[e];
          float mk = msks[e];
#pragma unroll
          for (int nt = 0; nt < 2; ++nt) {
            float v = silu_f(acc[mt][nt][q] + bv2[nt]) * mk;
            atomicAdd(agg + (size_t)r * D_F + c0 + nt * 16 + l15, v);
          }
        }
    }
    bar_lds();
  }
}

// ================= node kernel (MFMA, residual) =================
#define NOFF_A  0u
#define NOFF_M1 32768u
#define NODE_LDS 49152u

__global__ __launch_bounds__(256)
void egcl_node_kernel(const float* __restrict__ h, const float* __restrict__ agg,
                      const float* __restrict__ Wn1, const float* __restrict__ bn1,
                      const float* __restrict__ Wn2, const float* __restrict__ bn2,
                      float* __restrict__ out) {
  extern __shared__ __attribute__((aligned(16))) char smem[];
  const int tid  = threadIdx.x;
  const int lane = tid & 63;
  const int wv   = tid >> 6;
  const int l15  = lane & 15;
  const int lg   = lane >> 4;
  const int c0   = wv * 32;
  const int col0 = c0 + l15;
  const int base = blockIdx.x * 64;

  FragU bw1[8][2];
  FragU bw2[4][2];
#pragma unroll
  for (int kt = 0; kt < 8; ++kt)
#pragma unroll
    for (int nt = 0; nt < 2; ++nt) {
      const int col = col0 + nt * 16;
      const int kb = kt * 32 + lg * 8;
#pragma unroll
      for (int j = 0; j < 4; ++j)
        bw1[kt][nt].u[j] = cvt_pk_bf16(Wn1[(kb + 2 * j) * D_F + col],
                                       Wn1[(kb + 2 * j + 1) * D_F + col]);
    }
#pragma unroll
  for (int kt = 0; kt < 4; ++kt)
#pragma unroll
    for (int nt = 0; nt < 2; ++nt) {
      const int col = col0 + nt * 16;
      const int kb = kt * 32 + lg * 8;
#pragma unroll
      for (int j = 0; j < 4; ++j)
        bw2[kt][nt].u[j] = cvt_pk_bf16(Wn2[(kb + 2 * j) * D_F + col],
                                       Wn2[(kb + 2 * j + 1) * D_F + col]);
    }
  const float bv1[2] = {bn1[col0], bn1[col0 + 16]};
  const float bv2[2] = {bn2[col0], bn2[col0 + 16]};

  const int se = tid >> 2;
  const int sq = tid & 3;
  const unsigned sswz = (unsigned)((se & 7) << 4);
  const unsigned rswz = (unsigned)((l15 & 7) << 4);
  const int node = base + se;

#pragma unroll
  for (int p = 0; p < 2; ++p) {
    FragU w;
    if (node < N_NODES) {
      const f32x4* src = (const f32x4*)((p ? agg : h) + node * D_F + sq * 32);
#pragma unroll
      for (int j = 0; j < 4; ++j) {
        f32x4 x0 = src[2 * j], x1 = src[2 * j + 1];
        w.u[0] = cvt_pk_bf16(x0[0], x0[1]);
        w.u[1] = cvt_pk_bf16(x0[2], x0[3]);
        w.u[2] = cvt_pk_bf16(x1[0], x1[1]);
        w.u[3] = cvt_pk_bf16(x1[2], x1[3]);
        unsigned kb = (unsigned)(p * 256 + sq * 64 + j * 16);
        *(s16x8*)(smem + NOFF_A + (unsigned)(se * 512) + (kb ^ sswz)) = w.v;
      }
    } else {
      w.u[0] = w.u[1] = w.u[2] = w.u[3] = 0u;
#pragma unroll
      for (int j = 0; j < 4; ++j) {
        unsigned kb = (unsigned)(p * 256 + sq * 64 + j * 16);
        *(s16x8*)(smem + NOFF_A + (unsigned)(se * 512) + (kb ^ sswz)) = w.v;
      }
    }
  }
  bar_lds();

  f32x4 acc[4][2];
#pragma unroll
  for (int mt = 0; mt < 4; ++mt)
#pragma unroll
    for (int nt = 0; nt < 2; ++nt) acc[mt][nt] = (f32x4){0.f, 0.f, 0.f, 0.f};
#pragma unroll
  for (int ks = 0; ks < 8; ++ks) {
    s16x8 a[4];
    unsigned kb = ((unsigned)((ks * 32 + lg * 8) * 2)) ^ rswz;
#pragma unroll
    for (int mt = 0; mt < 4; ++mt)
      a[mt] = *(const s16x8*)(smem + NOFF_A + (unsigned)((mt * 16 + l15) * 512) + kb);
#pragma unroll
    for (int mt = 0; mt < 4; ++mt)
#pragma unroll
      for (int nt = 0; nt < 2; ++nt)
        acc[mt][nt] = __builtin_amdgcn_mfma_f32_16x16x32_bf16(a[mt], bw1[ks][nt].v,
                                                              acc[mt][nt], 0, 0, 0);
  }
#pragma unroll
  for (int mt = 0; mt < 4; ++mt)
#pragma unroll
    for (int nt = 0; nt < 2; ++nt)
#pragma unroll
      for (int q = 0; q < 4; ++q) {
        int e = mt * 16 + lg * 4 + q;
        float v = silu_f(acc[mt][nt][q] + bv1[nt]);
        *(unsigned short*)(smem + NOFF_M1 + (unsigned)(e * 256) +
                           ((unsigned)((c0 + nt * 16 + l15) * 2) ^
                            ((unsigned)((e & 7) << 4)))) =
            (unsigned short)cvt_pk_bf16(v, v);
      }
  bar_lds();

#pragma unroll
  for (int mt = 0; mt < 4; ++mt)
#pragma unroll
    for (int nt = 0; nt < 2; ++nt) acc[mt][nt] = (f32x4){0.f, 0.f, 0.f, 0.f};
#pragma unroll
  for (int ks = 0; ks < 4; ++ks) {
    s16x8 a[4];
    unsigned kb = ((unsigned)((ks * 32 + lg * 8) * 2)) ^ rswz;
#pragma unroll
    for (int mt = 0; mt < 4; ++mt)
      a[mt] = *(const s16x8*)(smem + NOFF_M1 + (unsigned)((mt * 16 + l15) * 256) + kb);
#pragma unroll
    for (int mt = 0; mt < 4; ++mt)
#pragma unroll
      for (int nt = 0; nt < 2; ++nt)
        acc[mt][nt] = __builtin_amdgcn_mfma_f32_16x16x32_bf16(a[mt], bw2[ks][nt].v,
                                                              acc[mt][nt], 0, 0, 0);
  }
#pragma unroll
  for (int mt = 0; mt < 4; ++mt)
#pragma unroll
    for (int q = 0; q < 4; ++q) {
      int nd = base + mt * 16 + lg * 4 + q;
      if (nd < N_NODES) {
#pragma unroll
        for (int nt = 0; nt < 2; ++nt) {
          int col = c0 + nt * 16 + l15;
          out[nd * D_F + col] = h[nd * D_F + col] + acc[mt][nt][q] + bv2[nt];
        }
      }
    }
}

extern "C" void kernel_launch(void* const* d_in, const int* in_sizes, int n_in,
                              void* d_out, int out_size, void* d_ws, size_t ws_size,
                              hipStream_t stream) {
  (void)in_sizes; (void)n_in; (void)out_size;
  const float* h         = (const float*)d_in[0];
  const float* coord     = (const float*)d_in[1];
  const float* edge_mask = (const float*)d_in[2];
  const float* We1       = (const float*)d_in[3];
  const float* be1       = (const float*)d_in[4];
  const float* We2       = (const float*)d_in[5];
  const float* be2       = (const float*)d_in[6];
  const float* Wn1       = (const float*)d_in[7];
  const float* bn1       = (const float*)d_in[8];
  const float* Wn2       = (const float*)d_in[9];
  const float* bn2       = (const float*)d_in[10];
  const int*   ei        = (const int*)d_in[11];
  float* out = (float*)d_out;
  char* ws = (char*)d_ws;
  float* agg = (float*)(ws + WS_AGG);

  hipFuncSetAttribute((const void*)egcl_edge2,
                      hipFuncAttributeMaxDynamicSharedMemorySize, (int)E2_LDS);
  hipFuncSetAttribute((const void*)egcl_node_kernel,
                      hipFuncAttributeMaxDynamicSharedMemorySize, (int)NODE_LDS);

  if (ws_size >= (size_t)WS_FULL_NEED) {
    unsigned* rcarr  = (unsigned*)(ws + WS_RC);
    float2*   radm   = (float2*)(ws + WS_RADM);
    int*      counts = (int*)(ws + WS_COUNTS);
    int*      cursor = (int*)(ws + WS_CURSOR);
    unsigned short* hbf = (unsigned short*)d_out;  // scratch; node kernel overwrites later

    // fused preprocessing via cooperative launch (prep+hist+scan+scatter, 1 dispatch)
    void* args[] = {(void*)&h, (void*)&hbf, (void*)&agg, (void*)&counts,
                    (void*)&cursor, (void*)&ei, (void*)&coord, (void*)&edge_mask,
                    (void*)&rcarr, (void*)&radm};
    hipError_t cerr = hipLaunchCooperativeKernel(
        (const void*)fused_pre_kernel, dim3(512), dim3(256), args, 0, stream);
    if (cerr != hipSuccess) {
      // fallback: sequential small kernels
      prep_kernel<<<(N_NODES * D_F / 4 + 255) / 256, 256, 0, stream>>>(h, hbf, agg, counts);
      hist_kernel<<<512, 256, 0, stream>>>(ei, counts);
      scan_kernel<<<1, 1024, 0, stream>>>(counts, cursor);
      scatter2_kernel<<<512, 256, 0, stream>>>(ei, coord, edge_mask, cursor, rcarr, radm);
    }
    egcl_edge2<<<GRID2, 256, E2_LDS, stream>>>(
        hbf, We1, be1, We2, be2, rcarr, radm, agg);
  } else if (ws_size >= (size_t)F_WS_NEED) {
    int* counts = (int*)(ws + F_WS_COUNTS);
    int* cursor = (int*)(ws + F_WS_CURSOR);
    int* perm   = (int*)(ws + F_WS_PERM);
    hipFuncSetAttribute((const void*)egcl_edge_fb<true>,
                        hipFuncAttributeMaxDynamicSharedMemorySize, (int)F_EDGE_LDS);
    hipMemsetAsync(ws, 0, F_WS_CURSOR, stream);
    hist_kernel<<<512, 256, 0, stream>>>(ei, counts);
    scan_kernel<<<1, 1024, 0, stream>>>(counts, cursor);
    scatter_kernel<<<512, 256, 0, stream>>>(ei, cursor, perm);
    egcl_edge_fb<true><<<768, 256, F_EDGE_LDS, stream>>>(
        h, coord, edge_mask, We1, be1, We2, be2, ei, perm, agg);
  } else {
    hipFuncSetAttribute((const void*)egcl_edge_fb<false>,
                        hipFuncAttributeMaxDynamicSharedMemorySize, (int)F_EDGE_LDS);
    hipMemsetAsync(agg, 0, (size_t)N_NODES * D_F * sizeof(float), stream);
    egcl_edge_fb<false><<<768, 256, F_EDGE_LDS, stream>>>(
        h, coord, edge_mask, We1, be1, We2, be2, ei, nullptr, agg);
  }
  egcl_node_kernel<<<(N_NODES + 63) / 64, 256, NODE_LDS, stream>>>(
      h, agg, Wn1, bn1, Wn2, bn2, out);
}

// Round 14
// 170.512 us; speedup vs baseline: 1.8326x; 1.8326x over previous
//
#include <hip/hip_runtime.h>

#define D_F 128
#define N_NODES 10000
#define N_EDGES 320000

// ---- workspace layout: FULL path ----
#define WS_AGG       0u
#define WS_RC        5120000u                  // E uints  (row | col<<16)
#define WS_RADM      6400000u                  // E float2 (radial, mask)
#define WS_COUNTS    8960000u                  // 10240 ints
#define WS_CURSOR    9000960u                  // 10240 ints
#define WS_DONE      9041920u                  // 1 int (+pad)
#define WS_FULL_NEED 9041984u
#define WS_OLD_NEED  9041920u

// ---- workspace layout: FALLBACK (R4) path ----
#define F_WS_COUNTS 5120000u
#define F_WS_CURSOR 5160960u
#define F_WS_PERM   5201920u
#define F_WS_NEED   (5201920u + 1280000u)

typedef short s16x8 __attribute__((ext_vector_type(8)));
typedef float f32x4 __attribute__((ext_vector_type(4)));

union FragU { s16x8 v; unsigned u[4]; };

__device__ __forceinline__ unsigned cvt_pk_bf16(float lo, float hi) {
  unsigned r;
  asm("v_cvt_pk_bf16_f32 %0, %1, %2" : "=v"(r) : "v"(lo), "v"(hi));
  return r;
}
__device__ __forceinline__ float bf2f(unsigned short b) {
  union { unsigned u; float f; } v; v.u = ((unsigned)b) << 16; return v.f;
}
__device__ __forceinline__ float silu_f(float x) {
  float t = __builtin_amdgcn_exp2f(x * -1.44269504089f);
  return x * __builtin_amdgcn_rcpf(1.0f + t);
}
__device__ __forceinline__ void bar_lds() {
  asm volatile("s_waitcnt lgkmcnt(0)" ::: "memory");
  __builtin_amdgcn_sched_barrier(0);
  __builtin_amdgcn_s_barrier();
  __builtin_amdgcn_sched_barrier(0);
}
__device__ __forceinline__ void bar_all() {
  asm volatile("s_waitcnt vmcnt(0) lgkmcnt(0)" ::: "memory");
  __builtin_amdgcn_sched_barrier(0);
  __builtin_amdgcn_s_barrier();
  __builtin_amdgcn_sched_barrier(0);
}
__device__ __forceinline__ void wait_vm0() {
  asm volatile("s_waitcnt vmcnt(0)" ::: "memory");
  __builtin_amdgcn_sched_barrier(0);
}
__device__ __forceinline__ void gload_lds16(const unsigned short* g, char* l) {
  __builtin_amdgcn_global_load_lds(
      (const __attribute__((address_space(1))) unsigned int*)g,
      (__attribute__((address_space(3))) unsigned int*)l, 16, 0, 0);
}

// ================= prep: h -> bf16 (into d_out), zero agg + counts + done ========
__global__ __launch_bounds__(256)
void prep_kernel(const float* __restrict__ h, unsigned short* __restrict__ hbf,
                 float* __restrict__ agg, int* __restrict__ counts,
                 int* __restrict__ done) {
  int g = blockIdx.x * 256 + threadIdx.x;
  int i = g * 4;
  if (i < N_NODES * D_F) {
    f32x4 v = *(const f32x4*)(h + i);
    *(unsigned*)(hbf + i)     = cvt_pk_bf16(v[0], v[1]);
    *(unsigned*)(hbf + i + 2) = cvt_pk_bf16(v[2], v[3]);
    *(f32x4*)(agg + i) = (f32x4){0.f, 0.f, 0.f, 0.f};
  }
  if (g < 10240) counts[g] = 0;
  if (done && g == 0) *done = 0;
}

// ================= hist + scan fused (last-block-done pattern) =================
__global__ __launch_bounds__(256)
void hist_scan_kernel(const int* __restrict__ ei, int* __restrict__ counts,
                      int* __restrict__ cursor, int* __restrict__ done) {
  for (int e = blockIdx.x * 256 + threadIdx.x; e < N_EDGES; e += gridDim.x * 256)
    atomicAdd(&counts[ei[e]], 1);
  __threadfence();
  __shared__ int last;
  if (threadIdx.x == 0) last = (atomicAdd(done, 1) == (int)gridDim.x - 1);
  __syncthreads();
  if (last) {
    __threadfence();
    __shared__ int sd[256];
    const int t = threadIdx.x;
    const int base = t * 40;
    int s = 0;
#pragma unroll 8
    for (int j = 0; j < 40; ++j) s += counts[base + j];
    sd[t] = s;
    __syncthreads();
    for (int off = 1; off < 256; off <<= 1) {
      int v = sd[t];
      int a = (t >= off) ? sd[t - off] : 0;
      __syncthreads();
      sd[t] = v + a;
      __syncthreads();
    }
    int run = sd[t] - s;  // exclusive prefix
#pragma unroll 8
    for (int j = 0; j < 40; ++j) {
      int c = counts[base + j];
      cursor[base + j] = run;
      run += c;
    }
  }
}

// ================= separate hist/scan (old-ws-size fallback) =================
__global__ __launch_bounds__(256)
void hist_kernel(const int* __restrict__ ei, int* __restrict__ counts) {
  for (int e = blockIdx.x * 256 + threadIdx.x; e < N_EDGES; e += gridDim.x * 256)
    atomicAdd(&counts[ei[e]], 1);
}

__global__ __launch_bounds__(1024)
void scan_kernel(const int* __restrict__ counts, int* __restrict__ cursor) {
  __shared__ int sd[1024];
  const int t = threadIdx.x;
  const int base = t * 10;
  int loc[10]; int s = 0;
#pragma unroll
  for (int j = 0; j < 10; ++j) { loc[j] = counts[base + j]; s += loc[j]; }
  sd[t] = s;
  __syncthreads();
  for (int off = 1; off < 1024; off <<= 1) {
    int v = sd[t];
    int a = (t >= off) ? sd[t - off] : 0;
    __syncthreads();
    sd[t] = v + a;
    __syncthreads();
  }
  int run = sd[t] - s;
#pragma unroll
  for (int j = 0; j < 10; ++j) { cursor[base + j] = run; run += loc[j]; }
}

__global__ __launch_bounds__(256)
void scatter2_kernel(const int* __restrict__ ei, const float* __restrict__ coord,
                     const float* __restrict__ edge_mask, int* __restrict__ cursor,
                     unsigned* __restrict__ rc, float2* __restrict__ radm) {
  for (int e = blockIdx.x * 256 + threadIdx.x; e < N_EDGES; e += gridDim.x * 256) {
    int r = ei[e], c = ei[N_EDGES + e];
    int pos = atomicAdd(&cursor[r], 1);
    float dx = coord[r * 3 + 0] - coord[c * 3 + 0];
    float dy = coord[r * 3 + 1] - coord[c * 3 + 1];
    float dz = coord[r * 3 + 2] - coord[c * 3 + 2];
    rc[pos] = (unsigned)r | ((unsigned)c << 16);
    radm[pos] = make_float2(dx * dx + dy * dy + dz * dz, edge_mask[e]);
  }
}

__global__ __launch_bounds__(256)
void scatter_kernel(const int* __restrict__ ei, int* __restrict__ cursor,
                    int* __restrict__ perm) {
  for (int e = blockIdx.x * 256 + threadIdx.x; e < N_EDGES; e += gridDim.x * 256) {
    int r = ei[e];
    int p = atomicAdd(&cursor[r], 1);
    perm[p] = e;
  }
}

// ================= edge kernel (R12 + f32 M2) ====
// LDS: A dbuf 2x16KB @0 ; M1 bf16 swz @32768 (8KB) ;
//      M2 f32 [32e][132f pad] @40960 (16896B) ; meta 3x512B @57856 ; total 59392
// M2 bank audit: bank=(4e+col)%32 -> ep2 writes 2-way (free), walk reads 2/bank.
#define TE2   32
#define GRID2 512
#define NT2   (N_EDGES / TE2)   // 10000
#define E2_M1   32768u
#define E2_M2   40960u
#define M2_STRIDE 528u          // 132 floats
#define E2_META 57856u
#define E2_LDS  59392u

__global__ __launch_bounds__(256)
void egcl_edge2(const unsigned short* __restrict__ hbf,
                const float* __restrict__ We1, const float* __restrict__ be1,
                const float* __restrict__ We2, const float* __restrict__ be2,
                const unsigned* __restrict__ rc, const float2* __restrict__ radm,
                float* __restrict__ agg) {
  extern __shared__ __attribute__((aligned(16))) char smem[];
  const int tid  = threadIdx.x;
  const int lane = tid & 63;
  const int wv   = tid >> 6;          // 0..3 : col group of 32
  const int l15  = lane & 15;
  const int lg   = lane >> 4;
  const int c0   = wv * 32;
  const int col0 = c0 + l15;
  const int le   = lane & 31;
  const int lh   = lane >> 5;

  FragU bw1[8][2];
  FragU bw2[4][2];
#pragma unroll
  for (int kt = 0; kt < 8; ++kt)
#pragma unroll
    for (int nt = 0; nt < 2; ++nt) {
      const int col = col0 + nt * 16;
      const int kb = kt * 32 + lg * 8;
#pragma unroll
      for (int j = 0; j < 4; ++j)
        bw1[kt][nt].u[j] = cvt_pk_bf16(We1[(kb + 2 * j) * D_F + col],
                                       We1[(kb + 2 * j + 1) * D_F + col]);
    }
#pragma unroll
  for (int kt = 0; kt < 4; ++kt)
#pragma unroll
    for (int nt = 0; nt < 2; ++nt) {
      const int col = col0 + nt * 16;
      const int kb = kt * 32 + lg * 8;
#pragma unroll
      for (int j = 0; j < 4; ++j)
        bw2[kt][nt].u[j] = cvt_pk_bf16(We2[(kb + 2 * j) * D_F + col],
                                       We2[(kb + 2 * j + 1) * D_F + col]);
    }
  const float bv1[2] = {be1[col0], be1[col0 + 16]};
  const float wlv[2] = {We1[256 * D_F + col0], We1[256 * D_F + col0 + 16]};
  const float bv2[2] = {be2[col0], be2[col0 + 16]};
  const unsigned rswz = (unsigned)((l15 & 7) << 4);

  const int bid = (int)blockIdx.x;
  int t = bid;
  unsigned crc; float2 crm;

  {
    crc = rc[t * TE2 + le];
    crm = radm[t * TE2 + le];
    if (tid < 32) {
      *(int*)(smem + E2_META + 0 + tid * 4)     = (int)(crc & 0xFFFFu);
      *(float*)(smem + E2_META + 128 + tid * 4) = crm.x;
      *(float*)(smem + E2_META + 256 + tid * 4) = crm.y;
    }
#pragma unroll
    for (int k = 0; k < 4; ++k) {
      int pr = wv * 4 + k;
      int cc = 2 * pr + lh;
      unsigned node = (cc < 16) ? (crc & 0xFFFFu) : (crc >> 16);
      gload_lds16(hbf + (size_t)node * D_F + (cc & 15) * 8,
                  smem + pr * 1024 + lane * 16);
    }
    int tn = t + GRID2; int tnc = (tn < NT2) ? tn : t;
    crc = rc[tnc * TE2 + le];
    crm = radm[tnc * TE2 + le];
  }
  bar_all();
  int p = 0;
  int ms = 0;

  for (; t < NT2; t += GRID2) {
    char* cur = smem + p * 16384;
    char* nxt = smem + (p ^ 1) * 16384;
    const int msn = (ms == 2) ? 0 : (ms + 1);
    const int mo = ms * 512, mn = msn * 512;
    int*   rowsL = (int*)(smem + E2_META + mo);
    float* radsL = (float*)(smem + E2_META + mo + 128);
    float* msksL = (float*)(smem + E2_META + mo + 256);

    {
#pragma unroll
      for (int k = 0; k < 4; ++k) {
        int pr = wv * 4 + k;
        int cc = 2 * pr + lh;
        unsigned node = (cc < 16) ? (crc & 0xFFFFu) : (crc >> 16);
        gload_lds16(hbf + (size_t)node * D_F + (cc & 15) * 8,
                    nxt + pr * 1024 + lane * 16);
      }
      if (tid < 32) {
        *(int*)(smem + E2_META + mn + 0 + tid * 4)     = (int)(crc & 0xFFFFu);
        *(float*)(smem + E2_META + mn + 128 + tid * 4) = crm.x;
        *(float*)(smem + E2_META + mn + 256 + tid * 4) = crm.y;
      }
    }
    int t2 = t + 2 * GRID2; int t2c = (t2 < NT2) ? t2 : bid;
    unsigned nrc = rc[t2c * TE2 + le];
    float2 nrm = radm[t2c * TE2 + le];

    f32x4 acc[2][2];
#pragma unroll
    for (int mt = 0; mt < 2; ++mt)
#pragma unroll
      for (int nt = 0; nt < 2; ++nt) acc[mt][nt] = (f32x4){0.f, 0.f, 0.f, 0.f};
    __builtin_amdgcn_s_setprio(1);
#pragma unroll
    for (int ks = 0; ks < 8; ++ks) {
      s16x8 a[2];
      const int chunk = ks * 4 + lg;
#pragma unroll
      for (int mt = 0; mt < 2; ++mt)
        a[mt] = *(const s16x8*)(cur + chunk * 512 + (mt * 16 + l15) * 16);
#pragma unroll
      for (int mt = 0; mt < 2; ++mt)
#pragma unroll
        for (int nt = 0; nt < 2; ++nt)
          acc[mt][nt] = __builtin_amdgcn_mfma_f32_16x16x32_bf16(a[mt], bw1[ks][nt].v,
                                                                acc[mt][nt], 0, 0, 0);
    }
    __builtin_amdgcn_s_setprio(0);

#pragma unroll
    for (int mt = 0; mt < 2; ++mt)
#pragma unroll
      for (int nt = 0; nt < 2; ++nt)
#pragma unroll
        for (int q = 0; q < 4; ++q) {
          int e = mt * 16 + lg * 4 + q;
          float v = acc[mt][nt][q] + bv1[nt] + radsL[e] * wlv[nt];
          v = silu_f(v);
          *(unsigned short*)(smem + E2_M1 + (unsigned)(e * 256) +
                             ((unsigned)((c0 + nt * 16 + l15) * 2) ^
                              ((unsigned)((e & 7) << 4)))) =
              (unsigned short)cvt_pk_bf16(v, v);
        }
    bar_lds();  // B1

    f32x4 acc2[2][2];
#pragma unroll
    for (int mt = 0; mt < 2; ++mt)
#pragma unroll
      for (int nt = 0; nt < 2; ++nt) acc2[mt][nt] = (f32x4){0.f, 0.f, 0.f, 0.f};
    __builtin_amdgcn_s_setprio(1);
#pragma unroll
    for (int ks = 0; ks < 4; ++ks) {
      s16x8 a[2];
      unsigned kb = ((unsigned)((ks * 32 + lg * 8) * 2)) ^ rswz;
#pragma unroll
      for (int mt = 0; mt < 2; ++mt)
        a[mt] = *(const s16x8*)(smem + E2_M1 +
                                (unsigned)((mt * 16 + l15) * 256) + kb);
#pragma unroll
      for (int mt = 0; mt < 2; ++mt)
#pragma unroll
        for (int nt = 0; nt < 2; ++nt)
          acc2[mt][nt] = __builtin_amdgcn_mfma_f32_16x16x32_bf16(a[mt], bw2[ks][nt].v,
                                                                 acc2[mt][nt], 0, 0, 0);
    }
    __builtin_amdgcn_s_setprio(0);
    // ---- ep2: silu*mask -> M2 (f32, padded stride; no cvt) ----
#pragma unroll
    for (int mt = 0; mt < 2; ++mt)
#pragma unroll
      for (int nt = 0; nt < 2; ++nt)
#pragma unroll
        for (int q = 0; q < 4; ++q) {
          int e = mt * 16 + lg * 4 + q;
          float v = silu_f(acc2[mt][nt][q] + bv2[nt]) * msksL[e];
          int col = c0 + nt * 16 + l15;
          *(float*)(smem + E2_M2 + (unsigned)(e * (int)M2_STRIDE) +
                    (unsigned)(col * 4)) = v;
        }
    wait_vm0();
    bar_lds();  // B2

    {
      const int q4 = tid >> 7, colw = tid & 127;
      const int eb = q4 * 16;
      float a = 0.f;
      int curR = rowsL[eb];
#pragma unroll
      for (int i = 0; i < 16; ++i) {
        int e = eb + i;
        float v = *(const float*)(smem + E2_M2 + (unsigned)(e * (int)M2_STRIDE) +
                                  (unsigned)(colw * 4));
        int r = rowsL[e];
        if (r != curR) {
          atomicAdd(agg + (size_t)curR * D_F + colw, a);
          a = 0.f; curR = r;
        }
        a += v;
      }
      atomicAdd(agg + (size_t)curR * D_F + colw, a);
    }
    crc = nrc; crm = nrm; p ^= 1; ms = msn;
  }
}

// ================= fallback edge kernel (R4, proven) =================
#define F_OFF_A    0u
#define F_OFF_M2   0u
#define F_OFF_M1   32768u
#define F_OFF_META 49152u
#define F_EDGE_LDS (49152u + 1024u)
#define NTILES (N_EDGES / 64)

template <bool SORTED>
__global__ __launch_bounds__(256)
void egcl_edge_fb(const float* __restrict__ h, const float* __restrict__ coord,
                  const float* __restrict__ edge_mask,
                  const float* __restrict__ We1, const float* __restrict__ be1,
                  const float* __restrict__ We2, const float* __restrict__ be2,
                  const int* __restrict__ ei, const int* __restrict__ perm,
                  float* __restrict__ agg) {
  extern __shared__ __attribute__((aligned(16))) char smem[];
  const int tid  = threadIdx.x;
  const int lane = tid & 63;
  const int wv   = tid >> 6;
  const int l15  = lane & 15;
  const int lg   = lane >> 4;
  const int c0   = wv * 32;
  const int col0 = c0 + l15;

  int*   rows = (int*)(smem + F_OFF_META);
  float* rads = (float*)(smem + F_OFF_META + 256);
  float* msks = (float*)(smem + F_OFF_META + 512);

  FragU bw1[8][2];
  FragU bw2[4][2];
#pragma unroll
  for (int kt = 0; kt < 8; ++kt)
#pragma unroll
    for (int nt = 0; nt < 2; ++nt) {
      const int col = col0 + nt * 16;
      const int kb = kt * 32 + lg * 8;
#pragma unroll
      for (int j = 0; j < 4; ++j)
        bw1[kt][nt].u[j] = cvt_pk_bf16(We1[(kb + 2 * j) * D_F + col],
                                       We1[(kb + 2 * j + 1) * D_F + col]);
    }
#pragma unroll
  for (int kt = 0; kt < 4; ++kt)
#pragma unroll
    for (int nt = 0; nt < 2; ++nt) {
      const int col = col0 + nt * 16;
      const int kb = kt * 32 + lg * 8;
#pragma unroll
      for (int j = 0; j < 4; ++j)
        bw2[kt][nt].u[j] = cvt_pk_bf16(We2[(kb + 2 * j) * D_F + col],
                                       We2[(kb + 2 * j + 1) * D_F + col]);
    }
  const float bv1[2] = {be1[col0], be1[col0 + 16]};
  const float wlv[2] = {We1[256 * D_F + col0], We1[256 * D_F + col0 + 16]};
  const float bv2[2] = {be2[col0], be2[col0 + 16]};

  const int se = tid >> 2;
  const int sq = tid & 3;
  const unsigned sswz = (unsigned)((se & 7) << 4);
  const unsigned rswz = (unsigned)((l15 & 7) << 4);

  for (int tile = (int)blockIdx.x; tile < NTILES; tile += (int)gridDim.x) {
    const int ebase = tile * 64;
    const int eidx = SORTED ? perm[ebase + se] : (ebase + se);
    const int n0 = ei[eidx];
    const int n1 = ei[N_EDGES + eidx];
    if (sq == 0) {
      float dx = coord[n0 * 3 + 0] - coord[n1 * 3 + 0];
      float dy = coord[n0 * 3 + 1] - coord[n1 * 3 + 1];
      float dz = coord[n0 * 3 + 2] - coord[n1 * 3 + 2];
      rows[se] = n0;
      rads[se] = dx * dx + dy * dy + dz * dz;
      msks[se] = edge_mask[eidx];
    }
#pragma unroll
    for (int pp = 0; pp < 2; ++pp) {
      const f32x4* src = (const f32x4*)(h + (pp ? n1 : n0) * D_F + sq * 32);
#pragma unroll
      for (int j = 0; j < 4; ++j) {
        f32x4 x0 = src[2 * j], x1 = src[2 * j + 1];
        FragU w;
        w.u[0] = cvt_pk_bf16(x0[0], x0[1]);
        w.u[1] = cvt_pk_bf16(x0[2], x0[3]);
        w.u[2] = cvt_pk_bf16(x1[0], x1[1]);
        w.u[3] = cvt_pk_bf16(x1[2], x1[3]);
        unsigned kb = (unsigned)(pp * 256 + sq * 64 + j * 16);
        *(s16x8*)(smem + F_OFF_A + (unsigned)(se * 512) + (kb ^ sswz)) = w.v;
      }
    }
    bar_lds();

    f32x4 acc[4][2];
#pragma unroll
    for (int mt = 0; mt < 4; ++mt)
#pragma unroll
      for (int nt = 0; nt < 2; ++nt) acc[mt][nt] = (f32x4){0.f, 0.f, 0.f, 0.f};
#pragma unroll
    for (int ks = 0; ks < 8; ++ks) {
      s16x8 a[4];
      unsigned kb = ((unsigned)((ks * 32 + lg * 8) * 2)) ^ rswz;
#pragma unroll
      for (int mt = 0; mt < 4; ++mt)
        a[mt] = *(const s16x8*)(smem + F_OFF_A + (unsigned)((mt * 16 + l15) * 512) + kb);
#pragma unroll
      for (int mt = 0; mt < 4; ++mt)
#pragma unroll
        for (int nt = 0; nt < 2; ++nt)
          acc[mt][nt] = __builtin_amdgcn_mfma_f32_16x16x32_bf16(a[mt], bw1[ks][nt].v,
                                                                acc[mt][nt], 0, 0, 0);
    }
#pragma unroll
    for (int mt = 0; mt < 4; ++mt)
#pragma unroll
      for (int nt = 0; nt < 2; ++nt)
#pragma unroll
        for (int q = 0; q < 4; ++q) {
          int e = mt * 16 + lg * 4 + q;
          float v = acc[mt][nt][q] + bv1[nt] + rads[e] * wlv[nt];
          v = silu_f(v);
          *(unsigned short*)(smem + F_OFF_M1 + (unsigned)(e * 256) +
                             ((unsigned)((c0 + nt * 16 + l15) * 2) ^
                              ((unsigned)((e & 7) << 4)))) =
              (unsigned short)cvt_pk_bf16(v, v);
        }
    bar_lds();

#pragma unroll
    for (int mt = 0; mt < 4; ++mt)
#pragma unroll
      for (int nt = 0; nt < 2; ++nt) acc[mt][nt] = (f32x4){0.f, 0.f, 0.f, 0.f};
#pragma unroll
    for (int ks = 0; ks < 4; ++ks) {
      s16x8 a[4];
      unsigned kb = ((unsigned)((ks * 32 + lg * 8) * 2)) ^ rswz;
#pragma unroll
      for (int mt = 0; mt < 4; ++mt)
        a[mt] = *(const s16x8*)(smem + F_OFF_M1 + (unsigned)((mt * 16 + l15) * 256) + kb);
#pragma unroll
      for (int mt = 0; mt < 4; ++mt)
#pragma unroll
        for (int nt = 0; nt < 2; ++nt)
          acc[mt][nt] = __builtin_amdgcn_mfma_f32_16x16x32_bf16(a[mt], bw2[ks][nt].v,
                                                                acc[mt][nt], 0, 0, 0);
    }
    if (SORTED) {
#pragma unroll
      for (int mt = 0; mt < 4; ++mt)
#pragma unroll
        for (int nt = 0; nt < 2; ++nt)
#pragma unroll
          for (int q = 0; q < 4; ++q) {
            int e = mt * 16 + lg * 4 + q;
            float v = silu_f(acc[mt][nt][q] + bv2[nt]) * msks[e];
            int col = c0 + nt * 16 + l15;
            *(unsigned short*)(smem + F_OFF_M2 + (unsigned)(e * 256) +
                               ((unsigned)(col * 2) ^ ((unsigned)((e & 7) << 4)))) =
                (unsigned short)cvt_pk_bf16(v, v);
          }
      bar_lds();
      {
        const int colw = tid & 127, half = tid >> 7;
        float a = 0.f;
        int cur = rows[half * 32];
#pragma unroll 8
        for (int i = 0; i < 32; ++i) {
          int e = half * 32 + i;
          float v = bf2f(*(const unsigned short*)(
              smem + F_OFF_M2 + (unsigned)(e * 256) +
              ((unsigned)(colw * 2) ^ ((unsigned)((e & 7) << 4)))));
          int r = rows[e];
          if (r != cur) { atomicAdd(agg + (size_t)cur * D_F + colw, a); a = 0.f; cur = r; }
          a += v;
        }
        atomicAdd(agg + (size_t)cur * D_F + colw, a);
      }
    } else {
#pragma unroll
      for (int mt = 0; mt < 4; ++mt)
#pragma unroll
        for (int q = 0; q < 4; ++q) {
          int e = mt * 16 + lg * 4 + q;
          int r = rows[e];
          float mk = msks[e];
#pragma unroll
          for (int nt = 0; nt < 2; ++nt) {
            float v = silu_f(acc[mt][nt][q] + bv2[nt]) * mk;
            atomicAdd(agg + (size_t)r * D_F + c0 + nt * 16 + l15, v);
          }
        }
    }
    bar_lds();
  }
}

// ================= node kernel (MFMA, residual) =================
#define NOFF_A  0u
#define NOFF_M1 32768u
#define NODE_LDS 49152u

__global__ __launch_bounds__(256)
void egcl_node_kernel(const float* __restrict__ h, const float* __restrict__ agg,
                      const float* __restrict__ Wn1, const float* __restrict__ bn1,
                      const float* __restrict__ Wn2, const float* __restrict__ bn2,
                      float* __restrict__ out) {
  extern __shared__ __attribute__((aligned(16))) char smem[];
  const int tid  = threadIdx.x;
  const int lane = tid & 63;
  const int wv   = tid >> 6;
  const int l15  = lane & 15;
  const int lg   = lane >> 4;
  const int c0   = wv * 32;
  const int col0 = c0 + l15;
  const int base = blockIdx.x * 64;

  FragU bw1[8][2];
  FragU bw2[4][2];
#pragma unroll
  for (int kt = 0; kt < 8; ++kt)
#pragma unroll
    for (int nt = 0; nt < 2; ++nt) {
      const int col = col0 + nt * 16;
      const int kb = kt * 32 + lg * 8;
#pragma unroll
      for (int j = 0; j < 4; ++j)
        bw1[kt][nt].u[j] = cvt_pk_bf16(Wn1[(kb + 2 * j) * D_F + col],
                                       Wn1[(kb + 2 * j + 1) * D_F + col]);
    }
#pragma unroll
  for (int kt = 0; kt < 4; ++kt)
#pragma unroll
    for (int nt = 0; nt < 2; ++nt) {
      const int col = col0 + nt * 16;
      const int kb = kt * 32 + lg * 8;
#pragma unroll
      for (int j = 0; j < 4; ++j)
        bw2[kt][nt].u[j] = cvt_pk_bf16(Wn2[(kb + 2 * j) * D_F + col],
                                       Wn2[(kb + 2 * j + 1) * D_F + col]);
    }
  const float bv1[2] = {bn1[col0], bn1[col0 + 16]};
  const float bv2[2] = {bn2[col0], bn2[col0 + 16]};

  const int se = tid >> 2;
  const int sq = tid & 3;
  const unsigned sswz = (unsigned)((se & 7) << 4);
  const unsigned rswz = (unsigned)((l15 & 7) << 4);
  const int node = base + se;

#pragma unroll
  for (int p = 0; p < 2; ++p) {
    FragU w;
    if (node < N_NODES) {
      const f32x4* src = (const f32x4*)((p ? agg : h) + node * D_F + sq * 32);
#pragma unroll
      for (int j = 0; j < 4; ++j) {
        f32x4 x0 = src[2 * j], x1 = src[2 * j + 1];
        w.u[0] = cvt_pk_bf16(x0[0], x0[1]);
        w.u[1] = cvt_pk_bf16(x0[2], x0[3]);
        w.u[2] = cvt_pk_bf16(x1[0], x1[1]);
        w.u[3] = cvt_pk_bf16(x1[2], x1[3]);
        unsigned kb = (unsigned)(p * 256 + sq * 64 + j * 16);
        *(s16x8*)(smem + NOFF_A + (unsigned)(se * 512) + (kb ^ sswz)) = w.v;
      }
    } else {
      w.u[0] = w.u[1] = w.u[2] = w.u[3] = 0u;
#pragma unroll
      for (int j = 0; j < 4; ++j) {
        unsigned kb = (unsigned)(p * 256 + sq * 64 + j * 16);
        *(s16x8*)(smem + NOFF_A + (unsigned)(se * 512) + (kb ^ sswz)) = w.v;
      }
    }
  }
  bar_lds();

  f32x4 acc[4][2];
#pragma unroll
  for (int mt = 0; mt < 4; ++mt)
#pragma unroll
    for (int nt = 0; nt < 2; ++nt) acc[mt][nt] = (f32x4){0.f, 0.f, 0.f, 0.f};
#pragma unroll
  for (int ks = 0; ks < 8; ++ks) {
    s16x8 a[4];
    unsigned kb = ((unsigned)((ks * 32 + lg * 8) * 2)) ^ rswz;
#pragma unroll
    for (int mt = 0; mt < 4; ++mt)
      a[mt] = *(const s16x8*)(smem + NOFF_A + (unsigned)((mt * 16 + l15) * 512) + kb);
#pragma unroll
    for (int mt = 0; mt < 4; ++mt)
#pragma unroll
      for (int nt = 0; nt < 2; ++nt)
        acc[mt][nt] = __builtin_amdgcn_mfma_f32_16x16x32_bf16(a[mt], bw1[ks][nt].v,
                                                              acc[mt][nt], 0, 0, 0);
  }
#pragma unroll
  for (int mt = 0; mt < 4; ++mt)
#pragma unroll
    for (int nt = 0; nt < 2; ++nt)
#pragma unroll
      for (int q = 0; q < 4; ++q) {
        int e = mt * 16 + lg * 4 + q;
        float v = silu_f(acc[mt][nt][q] + bv1[nt]);
        *(unsigned short*)(smem + NOFF_M1 + (unsigned)(e * 256) +
                           ((unsigned)((c0 + nt * 16 + l15) * 2) ^
                            ((unsigned)((e & 7) << 4)))) =
            (unsigned short)cvt_pk_bf16(v, v);
      }
  bar_lds();

#pragma unroll
  for (int mt = 0; mt < 4; ++mt)
#pragma unroll
    for (int nt = 0; nt < 2; ++nt) acc[mt][nt] = (f32x4){0.f, 0.f, 0.f, 0.f};
#pragma unroll
  for (int ks = 0; ks < 4; ++ks) {
    s16x8 a[4];
    unsigned kb = ((unsigned)((ks * 32 + lg * 8) * 2)) ^ rswz;
#pragma unroll
    for (int mt = 0; mt < 4; ++mt)
      a[mt] = *(const s16x8*)(smem + NOFF_M1 + (unsigned)((mt * 16 + l15) * 256) + kb);
#pragma unroll
    for (int mt = 0; mt < 4; ++mt)
#pragma unroll
      for (int nt = 0; nt < 2; ++nt)
        acc[mt][nt] = __builtin_amdgcn_mfma_f32_16x16x32_bf16(a[mt], bw2[ks][nt].v,
                                                              acc[mt][nt], 0, 0, 0);
  }
#pragma unroll
  for (int mt = 0; mt < 4; ++mt)
#pragma unroll
    for (int q = 0; q < 4; ++q) {
      int nd = base + mt * 16 + lg * 4 + q;
      if (nd < N_NODES) {
#pragma unroll
        for (int nt = 0; nt < 2; ++nt) {
          int col = c0 + nt * 16 + l15;
          out[nd * D_F + col] = h[nd * D_F + col] + acc[mt][nt][q] + bv2[nt];
        }
      }
    }
}

extern "C" void kernel_launch(void* const* d_in, const int* in_sizes, int n_in,
                              void* d_out, int out_size, void* d_ws, size_t ws_size,
                              hipStream_t stream) {
  (void)in_sizes; (void)n_in; (void)out_size;
  const float* h         = (const float*)d_in[0];
  const float* coord     = (const float*)d_in[1];
  const float* edge_mask = (const float*)d_in[2];
  const float* We1       = (const float*)d_in[3];
  const float* be1       = (const float*)d_in[4];
  const float* We2       = (const float*)d_in[5];
  const float* be2       = (const float*)d_in[6];
  const float* Wn1       = (const float*)d_in[7];
  const float* bn1       = (const float*)d_in[8];
  const float* Wn2       = (const float*)d_in[9];
  const float* bn2       = (const float*)d_in[10];
  const int*   ei        = (const int*)d_in[11];
  float* out = (float*)d_out;
  char* ws = (char*)d_ws;
  float* agg = (float*)(ws + WS_AGG);

  hipFuncSetAttribute((const void*)egcl_edge2,
                      hipFuncAttributeMaxDynamicSharedMemorySize, (int)E2_LDS);
  hipFuncSetAttribute((const void*)egcl_node_kernel,
                      hipFuncAttributeMaxDynamicSharedMemorySize, (int)NODE_LDS);

  if (ws_size >= (size_t)WS_OLD_NEED) {
    unsigned* rcarr  = (unsigned*)(ws + WS_RC);
    float2*   radm   = (float2*)(ws + WS_RADM);
    int*      counts = (int*)(ws + WS_COUNTS);
    int*      cursor = (int*)(ws + WS_CURSOR);
    unsigned short* hbf = (unsigned short*)d_out;  // scratch; node kernel overwrites later
    const bool fused = ws_size >= (size_t)WS_FULL_NEED;
    int* done = fused ? (int*)(ws + WS_DONE) : nullptr;

    prep_kernel<<<(N_NODES * D_F / 4 + 255) / 256, 256, 0, stream>>>(
        h, hbf, agg, counts, done);
    if (fused) {
      hist_scan_kernel<<<512, 256, 0, stream>>>(ei, counts, cursor, done);
    } else {
      hist_kernel<<<512, 256, 0, stream>>>(ei, counts);
      scan_kernel<<<1, 1024, 0, stream>>>(counts, cursor);
    }
    scatter2_kernel<<<512, 256, 0, stream>>>(ei, coord, edge_mask, cursor, rcarr, radm);
    egcl_edge2<<<GRID2, 256, E2_LDS, stream>>>(
        hbf, We1, be1, We2, be2, rcarr, radm, agg);
  } else if (ws_size >= (size_t)F_WS_NEED) {
    int* counts = (int*)(ws + F_WS_COUNTS);
    int* cursor = (int*)(ws + F_WS_CURSOR);
    int* perm   = (int*)(ws + F_WS_PERM);
    hipFuncSetAttribute((const void*)egcl_edge_fb<true>,
                        hipFuncAttributeMaxDynamicSharedMemorySize, (int)F_EDGE_LDS);
    hipMemsetAsync(ws, 0, F_WS_CURSOR, stream);
    hist_kernel<<<512, 256, 0, stream>>>(ei, counts);
    scan_kernel<<<1, 1024, 0, stream>>>(counts, cursor);
    scatter_kernel<<<512, 256, 0, stream>>>(ei, cursor, perm);
    egcl_edge_fb<true><<<768, 256, F_EDGE_LDS, stream>>>(
        h, coord, edge_mask, We1, be1, We2, be2, ei, perm, agg);
  } else {
    hipFuncSetAttribute((const void*)egcl_edge_fb<false>,
                        hipFuncAttributeMaxDynamicSharedMemorySize, (int)F_EDGE_LDS);
    hipMemsetAsync(agg, 0, (size_t)N_NODES * D_F * sizeof(float), stream);
    egcl_edge_fb<false><<<768, 256, F_EDGE_LDS, stream>>>(
        h, coord, edge_mask, We1, be1, We2, be2, ei, nullptr, agg);
  }
  egcl_node_kernel<<<(N_NODES + 63) / 64, 256, NODE_LDS, stream>>>(
      h, agg, Wn1, bn1, Wn2, bn2, out);
}

// Round 15
// 143.420 us; speedup vs baseline: 2.1787x; 1.1889x over previous
//
#include <hip/hip_runtime.h>

#define D_F 128
#define N_NODES 10000
#define N_EDGES 320000

// ---- workspace layout: FULL path ----
#define WS_AGG       0u
#define WS_RC        5120000u                  // E uints  (row | col<<16)
#define WS_RADM      6400000u                  // E float2 (radial, mask)
#define WS_COUNTS    8960000u                  // 10240 ints
#define WS_CURSOR    9000960u                  // 10240 ints
#define WS_FULL_NEED 9041920u

// ---- workspace layout: FALLBACK (R4) path ----
#define F_WS_COUNTS 5120000u
#define F_WS_CURSOR 5160960u
#define F_WS_PERM   5201920u
#define F_WS_NEED   (5201920u + 1280000u)

typedef short s16x8 __attribute__((ext_vector_type(8)));
typedef float f32x4 __attribute__((ext_vector_type(4)));

union FragU { s16x8 v; unsigned u[4]; };

__device__ __forceinline__ unsigned cvt_pk_bf16(float lo, float hi) {
  unsigned r;
  asm("v_cvt_pk_bf16_f32 %0, %1, %2" : "=v"(r) : "v"(lo), "v"(hi));
  return r;
}
__device__ __forceinline__ float bf2f(unsigned short b) {
  union { unsigned u; float f; } v; v.u = ((unsigned)b) << 16; return v.f;
}
__device__ __forceinline__ float silu_f(float x) {
  float t = __builtin_amdgcn_exp2f(x * -1.44269504089f);
  return x * __builtin_amdgcn_rcpf(1.0f + t);
}
__device__ __forceinline__ void bar_lds() {
  asm volatile("s_waitcnt lgkmcnt(0)" ::: "memory");
  __builtin_amdgcn_sched_barrier(0);
  __builtin_amdgcn_s_barrier();
  __builtin_amdgcn_sched_barrier(0);
}
__device__ __forceinline__ void bar_all() {
  asm volatile("s_waitcnt vmcnt(0) lgkmcnt(0)" ::: "memory");
  __builtin_amdgcn_sched_barrier(0);
  __builtin_amdgcn_s_barrier();
  __builtin_amdgcn_sched_barrier(0);
}
__device__ __forceinline__ void wait_vm0() {
  asm volatile("s_waitcnt vmcnt(0)" ::: "memory");
  __builtin_amdgcn_sched_barrier(0);
}
__device__ __forceinline__ void gload_lds16(const unsigned short* g, char* l) {
  __builtin_amdgcn_global_load_lds(
      (const __attribute__((address_space(1))) unsigned int*)g,
      (__attribute__((address_space(3))) unsigned int*)l, 16, 0, 0);
}

// ================= prep: h -> bf16 (into d_out), zero agg + counts =================
__global__ __launch_bounds__(256)
void prep_kernel(const float* __restrict__ h, unsigned short* __restrict__ hbf,
                 float* __restrict__ agg, int* __restrict__ counts) {
  int g = blockIdx.x * 256 + threadIdx.x;
  int i = g * 4;
  if (i < N_NODES * D_F) {
    f32x4 v = *(const f32x4*)(h + i);
    *(unsigned*)(hbf + i)     = cvt_pk_bf16(v[0], v[1]);
    *(unsigned*)(hbf + i + 2) = cvt_pk_bf16(v[2], v[3]);
    *(f32x4*)(agg + i) = (f32x4){0.f, 0.f, 0.f, 0.f};
  }
  if (g < 10240) counts[g] = 0;
}

// ================= sort: histogram / scan / scatter =================
__global__ __launch_bounds__(256)
void hist_kernel(const int* __restrict__ ei, int* __restrict__ counts) {
  for (int e = blockIdx.x * 256 + threadIdx.x; e < N_EDGES; e += gridDim.x * 256)
    atomicAdd(&counts[ei[e]], 1);
}

__global__ __launch_bounds__(1024)
void scan_kernel(const int* __restrict__ counts, int* __restrict__ cursor) {
  __shared__ int sd[1024];
  const int t = threadIdx.x;
  const int base = t * 10;
  int loc[10]; int s = 0;
#pragma unroll
  for (int j = 0; j < 10; ++j) { loc[j] = counts[base + j]; s += loc[j]; }
  sd[t] = s;
  __syncthreads();
  for (int off = 1; off < 1024; off <<= 1) {
    int v = sd[t];
    int a = (t >= off) ? sd[t - off] : 0;
    __syncthreads();
    sd[t] = v + a;
    __syncthreads();
  }
  int run = sd[t] - s;
#pragma unroll
  for (int j = 0; j < 10; ++j) { cursor[base + j] = run; run += loc[j]; }
}

// full path: write sorted flat arrays directly (no perm)
__global__ __launch_bounds__(256)
void scatter2_kernel(const int* __restrict__ ei, const float* __restrict__ coord,
                     const float* __restrict__ edge_mask, int* __restrict__ cursor,
                     unsigned* __restrict__ rc, float2* __restrict__ radm) {
  for (int e = blockIdx.x * 256 + threadIdx.x; e < N_EDGES; e += gridDim.x * 256) {
    int r = ei[e], c = ei[N_EDGES + e];
    int pos = atomicAdd(&cursor[r], 1);
    float dx = coord[r * 3 + 0] - coord[c * 3 + 0];
    float dy = coord[r * 3 + 1] - coord[c * 3 + 1];
    float dz = coord[r * 3 + 2] - coord[c * 3 + 2];
    rc[pos] = (unsigned)r | ((unsigned)c << 16);
    radm[pos] = make_float2(dx * dx + dy * dy + dz * dz, edge_mask[e]);
  }
}

// fallback path scatter: perm only
__global__ __launch_bounds__(256)
void scatter_kernel(const int* __restrict__ ei, int* __restrict__ cursor,
                    int* __restrict__ perm) {
  for (int e = blockIdx.x * 256 + threadIdx.x; e < N_EDGES; e += gridDim.x * 256) {
    int r = ei[e];
    int p = atomicAdd(&cursor[r], 1);
    perm[p] = e;
  }
}

// ================= edge kernel (R12 best: 2 barriers/tile, TE=32, 2 blk/CU) ====
// LDS: A dbuf 2x16KB @0 ; M1 @32768 (8KB) ; M2 @40960 (8KB) ; meta 3x512B @49152
#define TE2   32
#define GRID2 512
#define NT2   (N_EDGES / TE2)   // 10000
#define E2_M1   32768u
#define E2_M2   40960u
#define E2_META 49152u
#define E2_LDS  50688u

__global__ __launch_bounds__(256)
void egcl_edge2(const unsigned short* __restrict__ hbf,
                const float* __restrict__ We1, const float* __restrict__ be1,
                const float* __restrict__ We2, const float* __restrict__ be2,
                const unsigned* __restrict__ rc, const float2* __restrict__ radm,
                float* __restrict__ agg) {
  extern __shared__ __attribute__((aligned(16))) char smem[];
  const int tid  = threadIdx.x;
  const int lane = tid & 63;
  const int wv   = tid >> 6;          // 0..3 : col group of 32
  const int l15  = lane & 15;
  const int lg   = lane >> 4;
  const int c0   = wv * 32;
  const int col0 = c0 + l15;
  const int le   = lane & 31;         // edge index this lane tracks
  const int lh   = lane >> 5;         // chunk parity within DMA pair

  // ---- per-wave weight fragments in registers (bf16) : 32 cols/wave ----
  FragU bw1[8][2];
  FragU bw2[4][2];
#pragma unroll
  for (int kt = 0; kt < 8; ++kt)
#pragma unroll
    for (int nt = 0; nt < 2; ++nt) {
      const int col = col0 + nt * 16;
      const int kb = kt * 32 + lg * 8;
#pragma unroll
      for (int j = 0; j < 4; ++j)
        bw1[kt][nt].u[j] = cvt_pk_bf16(We1[(kb + 2 * j) * D_F + col],
                                       We1[(kb + 2 * j + 1) * D_F + col]);
    }
#pragma unroll
  for (int kt = 0; kt < 4; ++kt)
#pragma unroll
    for (int nt = 0; nt < 2; ++nt) {
      const int col = col0 + nt * 16;
      const int kb = kt * 32 + lg * 8;
#pragma unroll
      for (int j = 0; j < 4; ++j)
        bw2[kt][nt].u[j] = cvt_pk_bf16(We2[(kb + 2 * j) * D_F + col],
                                       We2[(kb + 2 * j + 1) * D_F + col]);
    }
  const float bv1[2] = {be1[col0], be1[col0 + 16]};
  const float wlv[2] = {We1[256 * D_F + col0], We1[256 * D_F + col0 + 16]};
  const float bv2[2] = {be2[col0], be2[col0 + 16]};
  const unsigned rswz = (unsigned)((l15 & 7) << 4);

  const int bid = (int)blockIdx.x;
  int t = bid;
  unsigned crc; float2 crm;

  // ---- prologue: stage tile t0 into buf0, meta(t0) slot0, prefetch meta(t1) ----
  {
    crc = rc[t * TE2 + le];
    crm = radm[t * TE2 + le];
    if (tid < 32) {
      *(int*)(smem + E2_META + 0 + tid * 4)     = (int)(crc & 0xFFFFu);
      *(float*)(smem + E2_META + 128 + tid * 4) = crm.x;
      *(float*)(smem + E2_META + 256 + tid * 4) = crm.y;
    }
#pragma unroll
    for (int k = 0; k < 4; ++k) {
      int pr = wv * 4 + k;              // pair 0..15 -> chunks 2pr, 2pr+1
      int cc = 2 * pr + lh;             // chunk 0..31 (k-slice of 8 bf16)
      unsigned node = (cc < 16) ? (crc & 0xFFFFu) : (crc >> 16);
      gload_lds16(hbf + (size_t)node * D_F + (cc & 15) * 8,
                  smem + pr * 1024 + lane * 16);
    }
    int tn = t + GRID2; int tnc = (tn < NT2) ? tn : t;
    crc = rc[tnc * TE2 + le];
    crm = radm[tnc * TE2 + le];
  }
  bar_all();
  int p = 0;
  int ms = 0;   // meta slot of current tile (0..2)

  for (; t < NT2; t += GRID2) {
    char* cur = smem + p * 16384;
    char* nxt = smem + (p ^ 1) * 16384;
    const int msn = (ms == 2) ? 0 : (ms + 1);
    const int mo = ms * 512, mn = msn * 512;
    int*   rowsL = (int*)(smem + E2_META + mo);
    float* radsL = (float*)(smem + E2_META + mo + 128);
    float* msksL = (float*)(smem + E2_META + mo + 256);

    // ---- step0: DMA A(t+1) -> nxt, meta(t+1) -> slot msn ----
    {
#pragma unroll
      for (int k = 0; k < 4; ++k) {
        int pr = wv * 4 + k;
        int cc = 2 * pr + lh;
        unsigned node = (cc < 16) ? (crc & 0xFFFFu) : (crc >> 16);
        gload_lds16(hbf + (size_t)node * D_F + (cc & 15) * 8,
                    nxt + pr * 1024 + lane * 16);
      }
      if (tid < 32) {
        *(int*)(smem + E2_META + mn + 0 + tid * 4)     = (int)(crc & 0xFFFFu);
        *(float*)(smem + E2_META + mn + 128 + tid * 4) = crm.x;
        *(float*)(smem + E2_META + mn + 256 + tid * 4) = crm.y;
      }
    }
    int t2 = t + 2 * GRID2; int t2c = (t2 < NT2) ? t2 : bid;
    unsigned nrc = rc[t2c * TE2 + le];
    float2 nrm = radm[t2c * TE2 + le];

    // ---- GEMM1 over A(t): 32 edges x 32 cols/wave ----
    f32x4 acc[2][2];
#pragma unroll
    for (int mt = 0; mt < 2; ++mt)
#pragma unroll
      for (int nt = 0; nt < 2; ++nt) acc[mt][nt] = (f32x4){0.f, 0.f, 0.f, 0.f};
    __builtin_amdgcn_s_setprio(1);
#pragma unroll
    for (int ks = 0; ks < 8; ++ks) {
      s16x8 a[2];
      const int chunk = ks * 4 + lg;
#pragma unroll
      for (int mt = 0; mt < 2; ++mt)
        a[mt] = *(const s16x8*)(cur + chunk * 512 + (mt * 16 + l15) * 16);
#pragma unroll
      for (int mt = 0; mt < 2; ++mt)
#pragma unroll
        for (int nt = 0; nt < 2; ++nt)
          acc[mt][nt] = __builtin_amdgcn_mfma_f32_16x16x32_bf16(a[mt], bw1[ks][nt].v,
                                                                acc[mt][nt], 0, 0, 0);
    }
    __builtin_amdgcn_s_setprio(0);

    // ---- ep1: +be1 +radial*wlast, silu -> M1 (M1 dead since B2(t-1)) ----
#pragma unroll
    for (int mt = 0; mt < 2; ++mt)
#pragma unroll
      for (int nt = 0; nt < 2; ++nt)
#pragma unroll
        for (int q = 0; q < 4; ++q) {
          int e = mt * 16 + lg * 4 + q;
          float v = acc[mt][nt][q] + bv1[nt] + radsL[e] * wlv[nt];
          v = silu_f(v);
          *(unsigned short*)(smem + E2_M1 + (unsigned)(e * 256) +
                             ((unsigned)((c0 + nt * 16 + l15) * 2) ^
                              ((unsigned)((e & 7) << 4)))) =
              (unsigned short)cvt_pk_bf16(v, v);
        }
    bar_lds();  // B1: M1 visible; also orders walk(t-1)->ep2(t) on M2

    // ---- GEMM2 over M1 ----
    f32x4 acc2[2][2];
#pragma unroll
    for (int mt = 0; mt < 2; ++mt)
#pragma unroll
      for (int nt = 0; nt < 2; ++nt) acc2[mt][nt] = (f32x4){0.f, 0.f, 0.f, 0.f};
    __builtin_amdgcn_s_setprio(1);
#pragma unroll
    for (int ks = 0; ks < 4; ++ks) {
      s16x8 a[2];
      unsigned kb = ((unsigned)((ks * 32 + lg * 8) * 2)) ^ rswz;
#pragma unroll
      for (int mt = 0; mt < 2; ++mt)
        a[mt] = *(const s16x8*)(smem + E2_M1 +
                                (unsigned)((mt * 16 + l15) * 256) + kb);
#pragma unroll
      for (int mt = 0; mt < 2; ++mt)
#pragma unroll
        for (int nt = 0; nt < 2; ++nt)
          acc2[mt][nt] = __builtin_amdgcn_mfma_f32_16x16x32_bf16(a[mt], bw2[ks][nt].v,
                                                                 acc2[mt][nt], 0, 0, 0);
    }
    __builtin_amdgcn_s_setprio(0);
    // ---- ep2: silu*mask -> M2 ----
#pragma unroll
    for (int mt = 0; mt < 2; ++mt)
#pragma unroll
      for (int nt = 0; nt < 2; ++nt)
#pragma unroll
        for (int q = 0; q < 4; ++q) {
          int e = mt * 16 + lg * 4 + q;
          float v = silu_f(acc2[mt][nt][q] + bv2[nt]) * msksL[e];
          int col = c0 + nt * 16 + l15;
          *(unsigned short*)(smem + E2_M2 + (unsigned)(e * 256) +
                             ((unsigned)(col * 2) ^ ((unsigned)((e & 7) << 4)))) =
              (unsigned short)cvt_pk_bf16(v, v);
        }
    // drain own DMAs BEFORE B2: after B2 every wave's DMA is complete+visible,
    // so GEMM1(t+1) needs no further sync on nxt.
    wait_vm0();
    bar_lds();  // B2: M2 visible + DMAs drained block-wide; M1 free

    // ---- walk: 2 threads/col x 16 edges, one atomic per row-run ----
    {
      const int q4 = tid >> 7, colw = tid & 127;
      const int eb = q4 * 16;
      float a = 0.f;
      int curR = rowsL[eb];
#pragma unroll
      for (int i = 0; i < 16; ++i) {
        int e = eb + i;
        float v = bf2f(*(const unsigned short*)(
            smem + E2_M2 + (unsigned)(e * 256) +
            ((unsigned)(colw * 2) ^ ((unsigned)((e & 7) << 4)))));
        int r = rowsL[e];
        if (r != curR) {
          atomicAdd(agg + (size_t)curR * D_F + colw, a);
          a = 0.f; curR = r;
        }
        a += v;
      }
      atomicAdd(agg + (size_t)curR * D_F + colw, a);
    }
    // no B3: meta slot reuse is 3-deep; all other hazards covered by B1/B2.
    crc = nrc; crm = nrm; p ^= 1; ms = msn;
  }
}

// ================= fallback edge kernel (R4, proven) =================
#define F_OFF_A    0u
#define F_OFF_M2   0u
#define F_OFF_M1   32768u
#define F_OFF_META 49152u
#define F_EDGE_LDS (49152u + 1024u)
#define NTILES (N_EDGES / 64)

template <bool SORTED>
__global__ __launch_bounds__(256)
void egcl_edge_fb(const float* __restrict__ h, const float* __restrict__ coord,
                  const float* __restrict__ edge_mask,
                  const float* __restrict__ We1, const float* __restrict__ be1,
                  const float* __restrict__ We2, const float* __restrict__ be2,
                  const int* __restrict__ ei, const int* __restrict__ perm,
                  float* __restrict__ agg) {
  extern __shared__ __attribute__((aligned(16))) char smem[];
  const int tid  = threadIdx.x;
  const int lane = tid & 63;
  const int wv   = tid >> 6;
  const int l15  = lane & 15;
  const int lg   = lane >> 4;
  const int c0   = wv * 32;
  const int col0 = c0 + l15;

  int*   rows = (int*)(smem + F_OFF_META);
  float* rads = (float*)(smem + F_OFF_META + 256);
  float* msks = (float*)(smem + F_OFF_META + 512);

  FragU bw1[8][2];
  FragU bw2[4][2];
#pragma unroll
  for (int kt = 0; kt < 8; ++kt)
#pragma unroll
    for (int nt = 0; nt < 2; ++nt) {
      const int col = col0 + nt * 16;
      const int kb = kt * 32 + lg * 8;
#pragma unroll
      for (int j = 0; j < 4; ++j)
        bw1[kt][nt].u[j] = cvt_pk_bf16(We1[(kb + 2 * j) * D_F + col],
                                       We1[(kb + 2 * j + 1) * D_F + col]);
    }
#pragma unroll
  for (int kt = 0; kt < 4; ++kt)
#pragma unroll
    for (int nt = 0; nt < 2; ++nt) {
      const int col = col0 + nt * 16;
      const int kb = kt * 32 + lg * 8;
#pragma unroll
      for (int j = 0; j < 4; ++j)
        bw2[kt][nt].u[j] = cvt_pk_bf16(We2[(kb + 2 * j) * D_F + col],
                                       We2[(kb + 2 * j + 1) * D_F + col]);
    }
  const float bv1[2] = {be1[col0], be1[col0 + 16]};
  const float wlv[2] = {We1[256 * D_F + col0], We1[256 * D_F + col0 + 16]};
  const float bv2[2] = {be2[col0], be2[col0 + 16]};

  const int se = tid >> 2;
  const int sq = tid & 3;
  const unsigned sswz = (unsigned)((se & 7) << 4);
  const unsigned rswz = (unsigned)((l15 & 7) << 4);

  for (int tile = (int)blockIdx.x; tile < NTILES; tile += (int)gridDim.x) {
    const int ebase = tile * 64;
    const int eidx = SORTED ? perm[ebase + se] : (ebase + se);
    const int n0 = ei[eidx];
    const int n1 = ei[N_EDGES + eidx];
    if (sq == 0) {
      float dx = coord[n0 * 3 + 0] - coord[n1 * 3 + 0];
      float dy = coord[n0 * 3 + 1] - coord[n1 * 3 + 1];
      float dz = coord[n0 * 3 + 2] - coord[n1 * 3 + 2];
      rows[se] = n0;
      rads[se] = dx * dx + dy * dy + dz * dz;
      msks[se] = edge_mask[eidx];
    }
#pragma unroll
    for (int pp = 0; pp < 2; ++pp) {
      const f32x4* src = (const f32x4*)(h + (pp ? n1 : n0) * D_F + sq * 32);
#pragma unroll
      for (int j = 0; j < 4; ++j) {
        f32x4 x0 = src[2 * j], x1 = src[2 * j + 1];
        FragU w;
        w.u[0] = cvt_pk_bf16(x0[0], x0[1]);
        w.u[1] = cvt_pk_bf16(x0[2], x0[3]);
        w.u[2] = cvt_pk_bf16(x1[0], x1[1]);
        w.u[3] = cvt_pk_bf16(x1[2], x1[3]);
        unsigned kb = (unsigned)(pp * 256 + sq * 64 + j * 16);
        *(s16x8*)(smem + F_OFF_A + (unsigned)(se * 512) + (kb ^ sswz)) = w.v;
      }
    }
    bar_lds();

    f32x4 acc[4][2];
#pragma unroll
    for (int mt = 0; mt < 4; ++mt)
#pragma unroll
      for (int nt = 0; nt < 2; ++nt) acc[mt][nt] = (f32x4){0.f, 0.f, 0.f, 0.f};
#pragma unroll
    for (int ks = 0; ks < 8; ++ks) {
      s16x8 a[4];
      unsigned kb = ((unsigned)((ks * 32 + lg * 8) * 2)) ^ rswz;
#pragma unroll
      for (int mt = 0; mt < 4; ++mt)
        a[mt] = *(const s16x8*)(smem + F_OFF_A + (unsigned)((mt * 16 + l15) * 512) + kb);
#pragma unroll
      for (int mt = 0; mt < 4; ++mt)
#pragma unroll
        for (int nt = 0; nt < 2; ++nt)
          acc[mt][nt] = __builtin_amdgcn_mfma_f32_16x16x32_bf16(a[mt], bw1[ks][nt].v,
                                                                acc[mt][nt], 0, 0, 0);
    }
#pragma unroll
    for (int mt = 0; mt < 4; ++mt)
#pragma unroll
      for (int nt = 0; nt < 2; ++nt)
#pragma unroll
        for (int q = 0; q < 4; ++q) {
          int e = mt * 16 + lg * 4 + q;
          float v = acc[mt][nt][q] + bv1[nt] + rads[e] * wlv[nt];
          v = silu_f(v);
          *(unsigned short*)(smem + F_OFF_M1 + (unsigned)(e * 256) +
                             ((unsigned)((c0 + nt * 16 + l15) * 2) ^
                              ((unsigned)((e & 7) << 4)))) =
              (unsigned short)cvt_pk_bf16(v, v);
        }
    bar_lds();

#pragma unroll
    for (int mt = 0; mt < 4; ++mt)
#pragma unroll
      for (int nt = 0; nt < 2; ++nt) acc[mt][nt] = (f32x4){0.f, 0.f, 0.f, 0.f};
#pragma unroll
    for (int ks = 0; ks < 4; ++ks) {
      s16x8 a[4];
      unsigned kb = ((unsigned)((ks * 32 + lg * 8) * 2)) ^ rswz;
#pragma unroll
      for (int mt = 0; mt < 4; ++mt)
        a[mt] = *(const s16x8*)(smem + F_OFF_M1 + (unsigned)((mt * 16 + l15) * 256) + kb);
#pragma unroll
      for (int mt = 0; mt < 4; ++mt)
#pragma unroll
        for (int nt = 0; nt < 2; ++nt)
          acc[mt][nt] = __builtin_amdgcn_mfma_f32_16x16x32_bf16(a[mt], bw2[ks][nt].v,
                                                                acc[mt][nt], 0, 0, 0);
    }
    if (SORTED) {
#pragma unroll
      for (int mt = 0; mt < 4; ++mt)
#pragma unroll
        for (int nt = 0; nt < 2; ++nt)
#pragma unroll
          for (int q = 0; q < 4; ++q) {
            int e = mt * 16 + lg * 4 + q;
            float v = silu_f(acc[mt][nt][q] + bv2[nt]) * msks[e];
            int col = c0 + nt * 16 + l15;
            *(unsigned short*)(smem + F_OFF_M2 + (unsigned)(e * 256) +
                               ((unsigned)(col * 2) ^ ((unsigned)((e & 7) << 4)))) =
                (unsigned short)cvt_pk_bf16(v, v);
          }
      bar_lds();
      {
        const int colw = tid & 127, half = tid >> 7;
        float a = 0.f;
        int cur = rows[half * 32];
#pragma unroll 8
        for (int i = 0; i < 32; ++i) {
          int e = half * 32 + i;
          float v = bf2f(*(const unsigned short*)(
              smem + F_OFF_M2 + (unsigned)(e * 256) +
              ((unsigned)(colw * 2) ^ ((unsigned)((e & 7) << 4)))));
          int r = rows[e];
          if (r != cur) { atomicAdd(agg + (size_t)cur * D_F + colw, a); a = 0.f; cur = r; }
          a += v;
        }
        atomicAdd(agg + (size_t)cur * D_F + colw, a);
      }
    } else {
#pragma unroll
      for (int mt = 0; mt < 4; ++mt)
#pragma unroll
        for (int q = 0; q < 4; ++q) {
          int e = mt * 16 + lg * 4 + q;
          int r = rows[e];
          float mk = msks[e];
#pragma unroll
          for (int nt = 0; nt < 2; ++nt) {
            float v = silu_f(acc[mt][nt][q] + bv2[nt]) * mk;
            atomicAdd(agg + (size_t)r * D_F + c0 + nt * 16 + l15, v);
          }
        }
    }
    bar_lds();
  }
}

// ================= node kernel (MFMA, residual) =================
#define NOFF_A  0u
#define NOFF_M1 32768u
#define NODE_LDS 49152u

__global__ __launch_bounds__(256)
void egcl_node_kernel(const float* __restrict__ h, const float* __restrict__ agg,
                      const float* __restrict__ Wn1, const float* __restrict__ bn1,
                      const float* __restrict__ Wn2, const float* __restrict__ bn2,
                      float* __restrict__ out) {
  extern __shared__ __attribute__((aligned(16))) char smem[];
  const int tid  = threadIdx.x;
  const int lane = tid & 63;
  const int wv   = tid >> 6;
  const int l15  = lane & 15;
  const int lg   = lane >> 4;
  const int c0   = wv * 32;
  const int col0 = c0 + l15;
  const int base = blockIdx.x * 64;

  FragU bw1[8][2];
  FragU bw2[4][2];
#pragma unroll
  for (int kt = 0; kt < 8; ++kt)
#pragma unroll
    for (int nt = 0; nt < 2; ++nt) {
      const int col = col0 + nt * 16;
      const int kb = kt * 32 + lg * 8;
#pragma unroll
      for (int j = 0; j < 4; ++j)
        bw1[kt][nt].u[j] = cvt_pk_bf16(Wn1[(kb + 2 * j) * D_F + col],
                                       Wn1[(kb + 2 * j + 1) * D_F + col]);
    }
#pragma unroll
  for (int kt = 0; kt < 4; ++kt)
#pragma unroll
    for (int nt = 0; nt < 2; ++nt) {
      const int col = col0 + nt * 16;
      const int kb = kt * 32 + lg * 8;
#pragma unroll
      for (int j = 0; j < 4; ++j)
        bw2[kt][nt].u[j] = cvt_pk_bf16(Wn2[(kb + 2 * j) * D_F + col],
                                       Wn2[(kb + 2 * j + 1) * D_F + col]);
    }
  const float bv1[2] = {bn1[col0], bn1[col0 + 16]};
  const float bv2[2] = {bn2[col0], bn2[col0 + 16]};

  const int se = tid >> 2;
  const int sq = tid & 3;
  const unsigned sswz = (unsigned)((se & 7) << 4);
  const unsigned rswz = (unsigned)((l15 & 7) << 4);
  const int node = base + se;

#pragma unroll
  for (int p = 0; p < 2; ++p) {
    FragU w;
    if (node < N_NODES) {
      const f32x4* src = (const f32x4*)((p ? agg : h) + node * D_F + sq * 32);
#pragma unroll
      for (int j = 0; j < 4; ++j) {
        f32x4 x0 = src[2 * j], x1 = src[2 * j + 1];
        w.u[0] = cvt_pk_bf16(x0[0], x0[1]);
        w.u[1] = cvt_pk_bf16(x0[2], x0[3]);
        w.u[2] = cvt_pk_bf16(x1[0], x1[1]);
        w.u[3] = cvt_pk_bf16(x1[2], x1[3]);
        unsigned kb = (unsigned)(p * 256 + sq * 64 + j * 16);
        *(s16x8*)(smem + NOFF_A + (unsigned)(se * 512) + (kb ^ sswz)) = w.v;
      }
    } else {
      w.u[0] = w.u[1] = w.u[2] = w.u[3] = 0u;
#pragma unroll
      for (int j = 0; j < 4; ++j) {
        unsigned kb = (unsigned)(p * 256 + sq * 64 + j * 16);
        *(s16x8*)(smem + NOFF_A + (unsigned)(se * 512) + (kb ^ sswz)) = w.v;
      }
    }
  }
  bar_lds();

  f32x4 acc[4][2];
#pragma unroll
  for (int mt = 0; mt < 4; ++mt)
#pragma unroll
    for (int nt = 0; nt < 2; ++nt) acc[mt][nt] = (f32x4){0.f, 0.f, 0.f, 0.f};
#pragma unroll
  for (int ks = 0; ks < 8; ++ks) {
    s16x8 a[4];
    unsigned kb = ((unsigned)((ks * 32 + lg * 8) * 2)) ^ rswz;
#pragma unroll
    for (int mt = 0; mt < 4; ++mt)
      a[mt] = *(const s16x8*)(smem + NOFF_A + (unsigned)((mt * 16 + l15) * 512) + kb);
#pragma unroll
    for (int mt = 0; mt < 4; ++mt)
#pragma unroll
      for (int nt = 0; nt < 2; ++nt)
        acc[mt][nt] = __builtin_amdgcn_mfma_f32_16x16x32_bf16(a[mt], bw1[ks][nt].v,
                                                              acc[mt][nt], 0, 0, 0);
  }
#pragma unroll
  for (int mt = 0; mt < 4; ++mt)
#pragma unroll
    for (int nt = 0; nt < 2; ++nt)
#pragma unroll
      for (int q = 0; q < 4; ++q) {
        int e = mt * 16 + lg * 4 + q;
        float v = silu_f(acc[mt][nt][q] + bv1[nt]);
        *(unsigned short*)(smem + NOFF_M1 + (unsigned)(e * 256) +
                           ((unsigned)((c0 + nt * 16 + l15) * 2) ^
                            ((unsigned)((e & 7) << 4)))) =
            (unsigned short)cvt_pk_bf16(v, v);
      }
  bar_lds();

#pragma unroll
  for (int mt = 0; mt < 4; ++mt)
#pragma unroll
    for (int nt = 0; nt < 2; ++nt) acc[mt][nt] = (f32x4){0.f, 0.f, 0.f, 0.f};
#pragma unroll
  for (int ks = 0; ks < 4; ++ks) {
    s16x8 a[4];
    unsigned kb = ((unsigned)((ks * 32 + lg * 8) * 2)) ^ rswz;
#pragma unroll
    for (int mt = 0; mt < 4; ++mt)
      a[mt] = *(const s16x8*)(smem + NOFF_M1 + (unsigned)((mt * 16 + l15) * 256) + kb);
#pragma unroll
    for (int mt = 0; mt < 4; ++mt)
#pragma unroll
      for (int nt = 0; nt < 2; ++nt)
        acc[mt][nt] = __builtin_amdgcn_mfma_f32_16x16x32_bf16(a[mt], bw2[ks][nt].v,
                                                              acc[mt][nt], 0, 0, 0);
  }
#pragma unroll
  for (int mt = 0; mt < 4; ++mt)
#pragma unroll
    for (int q = 0; q < 4; ++q) {
      int nd = base + mt * 16 + lg * 4 + q;
      if (nd < N_NODES) {
#pragma unroll
        for (int nt = 0; nt < 2; ++nt) {
          int col = c0 + nt * 16 + l15;
          out[nd * D_F + col] = h[nd * D_F + col] + acc[mt][nt][q] + bv2[nt];
        }
      }
    }
}

extern "C" void kernel_launch(void* const* d_in, const int* in_sizes, int n_in,
                              void* d_out, int out_size, void* d_ws, size_t ws_size,
                              hipStream_t stream) {
  (void)in_sizes; (void)n_in; (void)out_size;
  const float* h         = (const float*)d_in[0];
  const float* coord     = (const float*)d_in[1];
  const float* edge_mask = (const float*)d_in[2];
  const float* We1       = (const float*)d_in[3];
  const float* be1       = (const float*)d_in[4];
  const float* We2       = (const float*)d_in[5];
  const float* be2       = (const float*)d_in[6];
  const float* Wn1       = (const float*)d_in[7];
  const float* bn1       = (const float*)d_in[8];
  const float* Wn2       = (const float*)d_in[9];
  const float* bn2       = (const float*)d_in[10];
  const int*   ei        = (const int*)d_in[11];
  float* out = (float*)d_out;
  char* ws = (char*)d_ws;
  float* agg = (float*)(ws + WS_AGG);

  hipFuncSetAttribute((const void*)egcl_edge2,
                      hipFuncAttributeMaxDynamicSharedMemorySize, (int)E2_LDS);
  hipFuncSetAttribute((const void*)egcl_node_kernel,
                      hipFuncAttributeMaxDynamicSharedMemorySize, (int)NODE_LDS);

  if (ws_size >= (size_t)WS_FULL_NEED) {
    unsigned* rcarr  = (unsigned*)(ws + WS_RC);
    float2*   radm   = (float2*)(ws + WS_RADM);
    int*      counts = (int*)(ws + WS_COUNTS);
    int*      cursor = (int*)(ws + WS_CURSOR);
    unsigned short* hbf = (unsigned short*)d_out;  // scratch; node kernel overwrites later

    prep_kernel<<<(N_NODES * D_F / 4 + 255) / 256, 256, 0, stream>>>(h, hbf, agg, counts);
    hist_kernel<<<512, 256, 0, stream>>>(ei, counts);
    scan_kernel<<<1, 1024, 0, stream>>>(counts, cursor);
    scatter2_kernel<<<512, 256, 0, stream>>>(ei, coord, edge_mask, cursor, rcarr, radm);
    egcl_edge2<<<GRID2, 256, E2_LDS, stream>>>(
        hbf, We1, be1, We2, be2, rcarr, radm, agg);
  } else if (ws_size >= (size_t)F_WS_NEED) {
    int* counts = (int*)(ws + F_WS_COUNTS);
    int* cursor = (int*)(ws + F_WS_CURSOR);
    int* perm   = (int*)(ws + F_WS_PERM);
    hipFuncSetAttribute((const void*)egcl_edge_fb<true>,
                        hipFuncAttributeMaxDynamicSharedMemorySize, (int)F_EDGE_LDS);
    hipMemsetAsync(ws, 0, F_WS_CURSOR, stream);
    hist_kernel<<<512, 256, 0, stream>>>(ei, counts);
    scan_kernel<<<1, 1024, 0, stream>>>(counts, cursor);
    scatter_kernel<<<512, 256, 0, stream>>>(ei, cursor, perm);
    egcl_edge_fb<true><<<768, 256, F_EDGE_LDS, stream>>>(
        h, coord, edge_mask, We1, be1, We2, be2, ei, perm, agg);
  } else {
    hipFuncSetAttribute((const void*)egcl_edge_fb<false>,
                        hipFuncAttributeMaxDynamicSharedMemorySize, (int)F_EDGE_LDS);
    hipMemsetAsync(agg, 0, (size_t)N_NODES * D_F * sizeof(float), stream);
    egcl_edge_fb<false><<<768, 256, F_EDGE_LDS, stream>>>(
        h, coord, edge_mask, We1, be1, We2, be2, ei, nullptr, agg);
  }
  egcl_node_kernel<<<(N_NODES + 63) / 64, 256, NODE_LDS, stream>>>(
      h, agg, Wn1, bn1, Wn2, bn2, out);
}